// Round 1
// baseline (579.460 us; speedup 1.0000x reference)
//
#include <hip/hip_runtime.h>
#include <hip/hip_bf16.h>

#define B_ 8
#define L_ 4096
#define C_ 256
#define H_ 8
#define D_ 32
#define CHUNK_ 128
#define NC_ 32
#define M_ (B_*L_)   // 32768

// ---------------------------------------------------------------------------
// Kernel 1: qkv = (x + rel_pos) @ qkv_w^T   (M=32768, N=768, K=256)
// 64x64 tile, BK=16, 256 threads, 4x4 per thread, f32.
// ---------------------------------------------------------------------------
__global__ __launch_bounds__(256) void k_qkv_gemm(
    const float* __restrict__ x, const float* __restrict__ rel,
    const float* __restrict__ w, float* __restrict__ qkv)
{
    __shared__ float As[16 * 65];
    __shared__ float Bs[16 * 65];
    const int tid = threadIdx.x;
    const int n0 = blockIdx.x * 64;
    const int m0 = blockIdx.y * 64;
    const int tx = tid & 15, ty = tid >> 4;
    const int lrow = tid >> 2;         // 0..63
    const int lcol = (tid & 3) << 2;   // 0,4,8,12
    const int gm = m0 + lrow;
    const int l  = gm & (L_ - 1);
    const float4* xrow = (const float4*)(x   + (size_t)gm * C_);
    const float4* rrow = (const float4*)(rel + (size_t)l  * C_);
    const float4* wrow = (const float4*)(w   + (size_t)(n0 + lrow) * C_);

    float acc[4][4] = {};
    for (int k0 = 0; k0 < C_; k0 += 16) {
        const int c4 = (k0 + lcol) >> 2;
        float4 a4 = xrow[c4];
        float4 r4 = rrow[c4];
        a4.x += r4.x; a4.y += r4.y; a4.z += r4.z; a4.w += r4.w;
        float4 b4 = wrow[c4];
        As[(lcol + 0) * 65 + lrow] = a4.x;
        As[(lcol + 1) * 65 + lrow] = a4.y;
        As[(lcol + 2) * 65 + lrow] = a4.z;
        As[(lcol + 3) * 65 + lrow] = a4.w;
        Bs[(lcol + 0) * 65 + lrow] = b4.x;
        Bs[(lcol + 1) * 65 + lrow] = b4.y;
        Bs[(lcol + 2) * 65 + lrow] = b4.z;
        Bs[(lcol + 3) * 65 + lrow] = b4.w;
        __syncthreads();
#pragma unroll
        for (int kk = 0; kk < 16; ++kk) {
            float a[4], b[4];
#pragma unroll
            for (int i = 0; i < 4; ++i) a[i] = As[kk * 65 + ty * 4 + i];
#pragma unroll
            for (int j = 0; j < 4; ++j) b[j] = Bs[kk * 65 + tx * 4 + j];
#pragma unroll
            for (int i = 0; i < 4; ++i)
#pragma unroll
                for (int j = 0; j < 4; ++j) acc[i][j] += a[i] * b[j];
        }
        __syncthreads();
    }
#pragma unroll
    for (int i = 0; i < 4; ++i) {
        float* orow = qkv + (size_t)(m0 + ty * 4 + i) * 768 + n0 + tx * 4;
#pragma unroll
        for (int j = 0; j < 4; ++j) orow[j] = acc[i][j];
    }
}

// ---------------------------------------------------------------------------
// Kernel 2: RMS-norm q and k rows (D=32) in place. 8 rows / 256-thread block.
// ---------------------------------------------------------------------------
__global__ __launch_bounds__(256) void k_rmsnorm(
    float* __restrict__ qkv, const float* __restrict__ qg, const float* __restrict__ kg)
{
    const int rid  = blockIdx.x * 8 + (threadIdx.x >> 5);
    const int lane = threadIdx.x & 31;
    const int s    = rid >> 18;             // 0 = q, 1 = k  (M*H = 2^18)
    const int rem  = rid & ((M_ * H_) - 1);
    const int m    = rem >> 3;
    const int h    = rem & 7;
    float* p = qkv + (size_t)m * 768 + s * 256 + h * 32;
    float v = p[lane];
    if (s == 0) v *= 0.17677669529663687f;   // D^{-1/2}
    float ss = v * v;
    ss += __shfl_xor(ss, 16);
    ss += __shfl_xor(ss, 8);
    ss += __shfl_xor(ss, 4);
    ss += __shfl_xor(ss, 2);
    ss += __shfl_xor(ss, 1);
    const float nrm = sqrtf(ss);
    const float g = (s == 0 ? qg : kg)[h * 32 + lane];
    p[lane] = v / fmaxf(nrm, 1e-12f) * 5.656854249492381f * g;  // * sqrt(D) * gamma
}

// ---------------------------------------------------------------------------
// Kernel 3: per-chunk KV contribution  KV[d][e] = sum_pos kdecay[pos]*k[pos][d]*v[pos][e]
// one block per (b,h,chunk), 256 threads.
// ---------------------------------------------------------------------------
__global__ __launch_bounds__(256) void k_chunk_kv(
    const float* __restrict__ qkv, float* __restrict__ kvbuf)
{
    __shared__ float ks[CHUNK_ * 32];
    __shared__ float vs[CHUNK_ * 32];
    const int blk = blockIdx.x;
    const int n  = blk & 31;
    const int bh = blk >> 5;
    const int h  = bh & 7;
    const int b  = bh >> 3;
    const float slope = exp2f(-(float)(h + 1));
    const int tid = threadIdx.x;
    const size_t rowbase = ((size_t)b * L_ + n * CHUNK_) * 768 + 256 + h * 32;
#pragma unroll
    for (int i = 0; i < 4; ++i) {
        int flat = i * 256 + tid;          // float4 index 0..1023
        int pos  = flat >> 3;
        int quad = flat & 7;
        const float* kp = qkv + rowbase + (size_t)pos * 768 + quad * 4;
        float4 k4 = *(const float4*)kp;
        float4 v4 = *(const float4*)(kp + 256);
        float kd = __expf(-slope * (float)(CHUNK_ - pos));
        ks[pos * 32 + quad * 4 + 0] = k4.x * kd;
        ks[pos * 32 + quad * 4 + 1] = k4.y * kd;
        ks[pos * 32 + quad * 4 + 2] = k4.z * kd;
        ks[pos * 32 + quad * 4 + 3] = k4.w * kd;
        *(float4*)&vs[pos * 32 + quad * 4] = v4;
    }
    __syncthreads();
    const int e   = tid & 31;
    const int dd0 = tid >> 5;   // 0..7
    float acc[4] = {0.f, 0.f, 0.f, 0.f};
    for (int pos = 0; pos < CHUNK_; ++pos) {
        float vv = vs[pos * 32 + e];
        acc[0] += ks[pos * 32 + dd0 +  0] * vv;
        acc[1] += ks[pos * 32 + dd0 +  8] * vv;
        acc[2] += ks[pos * 32 + dd0 + 16] * vv;
        acc[3] += ks[pos * 32 + dd0 + 24] * vv;
    }
    float* out = kvbuf + (size_t)blk * 1024;
#pragma unroll
    for (int i = 0; i < 4; ++i) out[(dd0 + i * 8) * 32 + e] = acc[i];
}

// ---------------------------------------------------------------------------
// Kernel 4: in-place scan over chunks: kvbuf[bh][n] <- state before chunk n.
// 64 blocks (one per b,h), 256 threads x float4 = 1024 state elements.
// ---------------------------------------------------------------------------
__global__ __launch_bounds__(256) void k_scan(float* __restrict__ kvbuf)
{
    const int bh = blockIdx.x;
    const int tid = threadIdx.x;
    const float slope = exp2f(-(float)((bh & 7) + 1));
    const float bd = __expf(-slope * (float)CHUNK_);
    float4 st = {0.f, 0.f, 0.f, 0.f};
    float4* base = (float4*)(kvbuf + (size_t)bh * NC_ * 1024) + tid;
    for (int n = 0; n < NC_; ++n) {
        float4 tmp = base[n * 256];
        base[n * 256] = st;
        st.x = bd * st.x + tmp.x;
        st.y = bd * st.y + tmp.y;
        st.z = bd * st.z + tmp.z;
        st.w = bd * st.w + tmp.w;
    }
}

// ---------------------------------------------------------------------------
// Kernel 5: per-chunk output = intra (masked) + inter (q*qdecay @ kv_state).
// one block per (b,h,chunk), 128 threads = one row each.
// ---------------------------------------------------------------------------
__global__ __launch_bounds__(128) void k_attn_out(
    const float* __restrict__ qkv, const float* __restrict__ kvbuf,
    float* __restrict__ attn_o)
{
    __shared__ float ks[CHUNK_ * 32];
    __shared__ float vs[CHUNK_ * 32];
    __shared__ float kvs[32 * 32];
    __shared__ float ejs[CHUNK_];
    const int blk = blockIdx.x;
    const int n  = blk & 31;
    const int bh = blk >> 5;
    const int h  = bh & 7;
    const int b  = bh >> 3;
    const float slope = exp2f(-(float)(h + 1));
    const int tid = threadIdx.x;   // row i, 0..127
    const size_t rowbase = ((size_t)b * L_ + n * CHUNK_) * 768 + h * 32;
#pragma unroll
    for (int i4 = 0; i4 < 8; ++i4) {
        int flat = i4 * 128 + tid;
        int pos  = flat >> 3;
        int quad = flat & 7;
        const float* kp = qkv + rowbase + (size_t)pos * 768 + 256 + quad * 4;
        *(float4*)&ks[pos * 32 + quad * 4] = *(const float4*)kp;
        *(float4*)&vs[pos * 32 + quad * 4] = *(const float4*)(kp + 256);
    }
    const float* kvp = kvbuf + (size_t)blk * 1024;
#pragma unroll
    for (int i = 0; i < 2; ++i)
        *(float4*)&kvs[i * 512 + tid * 4] = *(const float4*)&kvp[i * 512 + tid * 4];
    ejs[tid] = __expf(slope * (float)tid);
    __syncthreads();

    float q[32];
    const float* qp = qkv + rowbase + (size_t)tid * 768;
#pragma unroll
    for (int d4 = 0; d4 < 8; ++d4) *(float4*)&q[d4 * 4] = *(const float4*)(qp + d4 * 4);

    float o[32];
#pragma unroll
    for (int e = 0; e < 32; ++e) o[e] = 0.f;
    // inter: o = (q * qdecay) @ kv_state
    for (int d = 0; d < 32; ++d) {
        float coef = q[d];
#pragma unroll
        for (int e = 0; e < 32; ++e) o[e] += coef * kvs[d * 32 + e];
    }
    const float qdecay = __expf(-slope * (float)tid);
#pragma unroll
    for (int e = 0; e < 32; ++e) o[e] *= qdecay;
    // intra: sum_{j<=i} exp(-s(i-j)) (q_i . k_j) v_j
    for (int j = 0; j <= tid; ++j) {
        float dot = 0.f;
#pragma unroll
        for (int d = 0; d < 32; ++d) dot += q[d] * ks[j * 32 + d];
        float wgt = qdecay * ejs[j] * dot;
#pragma unroll
        for (int e = 0; e < 32; ++e) o[e] += wgt * vs[j * 32 + e];
    }
    float* op = attn_o + ((size_t)b * L_ + n * CHUNK_ + tid) * C_ + h * 32;
#pragma unroll
    for (int e4 = 0; e4 < 8; ++e4) {
        float4 o4 = { o[e4*4+0], o[e4*4+1], o[e4*4+2], o[e4*4+3] };
        *(float4*)(op + e4 * 4) = o4;
    }
}

// ---------------------------------------------------------------------------
// Kernel 6: out = attn @ proj_w^T + proj_b   (M=32768, N=256, K=256)
// ---------------------------------------------------------------------------
__global__ __launch_bounds__(256) void k_proj_gemm(
    const float* __restrict__ a, const float* __restrict__ w,
    const float* __restrict__ bias, float* __restrict__ out)
{
    __shared__ float As[16 * 65];
    __shared__ float Bs[16 * 65];
    const int tid = threadIdx.x;
    const int n0 = blockIdx.x * 64;
    const int m0 = blockIdx.y * 64;
    const int tx = tid & 15, ty = tid >> 4;
    const int lrow = tid >> 2;
    const int lcol = (tid & 3) << 2;
    const float4* arow = (const float4*)(a + (size_t)(m0 + lrow) * C_);
    const float4* wrow = (const float4*)(w + (size_t)(n0 + lrow) * C_);

    float acc[4][4] = {};
    for (int k0 = 0; k0 < C_; k0 += 16) {
        const int c4 = (k0 + lcol) >> 2;
        float4 a4 = arow[c4];
        float4 b4 = wrow[c4];
        As[(lcol + 0) * 65 + lrow] = a4.x;
        As[(lcol + 1) * 65 + lrow] = a4.y;
        As[(lcol + 2) * 65 + lrow] = a4.z;
        As[(lcol + 3) * 65 + lrow] = a4.w;
        Bs[(lcol + 0) * 65 + lrow] = b4.x;
        Bs[(lcol + 1) * 65 + lrow] = b4.y;
        Bs[(lcol + 2) * 65 + lrow] = b4.z;
        Bs[(lcol + 3) * 65 + lrow] = b4.w;
        __syncthreads();
#pragma unroll
        for (int kk = 0; kk < 16; ++kk) {
            float av[4], bv[4];
#pragma unroll
            for (int i = 0; i < 4; ++i) av[i] = As[kk * 65 + ty * 4 + i];
#pragma unroll
            for (int j = 0; j < 4; ++j) bv[j] = Bs[kk * 65 + tx * 4 + j];
#pragma unroll
            for (int i = 0; i < 4; ++i)
#pragma unroll
                for (int j = 0; j < 4; ++j) acc[i][j] += av[i] * bv[j];
        }
        __syncthreads();
    }
#pragma unroll
    for (int i = 0; i < 4; ++i) {
        float* orow = out + (size_t)(m0 + ty * 4 + i) * C_ + n0 + tx * 4;
#pragma unroll
        for (int j = 0; j < 4; ++j) orow[j] = acc[i][j] + bias[n0 + tx * 4 + j];
    }
}

// ---------------------------------------------------------------------------
extern "C" void kernel_launch(void* const* d_in, const int* in_sizes, int n_in,
                              void* d_out, int out_size, void* d_ws, size_t ws_size,
                              hipStream_t stream)
{
    const float* x     = (const float*)d_in[0];
    const float* rel   = (const float*)d_in[1];
    const float* qkv_w = (const float*)d_in[2];
    const float* qg    = (const float*)d_in[3];
    const float* kg    = (const float*)d_in[4];
    const float* pw    = (const float*)d_in[5];
    const float* pb    = (const float*)d_in[6];
    float* out = (float*)d_out;
    float* ws  = (float*)d_ws;

    float* qkv  = ws;                                  // M*768      = 25165824 f
    float* attn = ws + (size_t)25165824;               // M*256      =  8388608 f
    float* kvb  = ws + (size_t)25165824 + 8388608;     // 64*32*1024 =  2097152 f

    k_qkv_gemm<<<dim3(12, 512), 256, 0, stream>>>(x, rel, qkv_w, qkv);
    k_rmsnorm<<<65536, 256, 0, stream>>>(qkv, qg, kg);
    k_chunk_kv<<<2048, 256, 0, stream>>>(qkv, kvb);
    k_scan<<<64, 256, 0, stream>>>(kvb);
    k_attn_out<<<2048, 128, 0, stream>>>(qkv, kvb, attn);
    k_proj_gemm<<<dim3(4, 512), 256, 0, stream>>>(attn, pw, pb, out);
}

// Round 2
// 304.581 us; speedup vs baseline: 1.9025x; 1.9025x over previous
//
#include <hip/hip_runtime.h>
#include <hip/hip_bf16.h>

#define B_ 8
#define L_ 4096
#define C_ 256
#define H_ 8
#define D_ 32
#define CHUNK_ 128
#define NC_ 32
#define M_ (B_*L_)   // 32768

typedef __bf16 bf16x8 __attribute__((ext_vector_type(8)));
typedef __bf16 bf16x4 __attribute__((ext_vector_type(4)));
typedef float  f32x4  __attribute__((ext_vector_type(4)));

#define GLOAD_LDS16(g, l) __builtin_amdgcn_global_load_lds( \
    (const __attribute__((address_space(1))) unsigned int*)(g), \
    (__attribute__((address_space(3))) unsigned int*)(l), 16, 0, 0)

// ---------------------------------------------------------------------------
// Cast kernels: h = bf16(x + rel_pos); weights -> bf16
// ---------------------------------------------------------------------------
__global__ __launch_bounds__(256) void k_cast_h(
    const float* __restrict__ x, const float* __restrict__ rel, __bf16* __restrict__ h)
{
    const int i = (blockIdx.x * 256 + threadIdx.x) * 4;
    float4 xv = *(const float4*)(x + i);
    float4 rv = *(const float4*)(rel + (i & (L_ * C_ - 1)));
    bf16x4 o = { (__bf16)(xv.x + rv.x), (__bf16)(xv.y + rv.y),
                 (__bf16)(xv.z + rv.z), (__bf16)(xv.w + rv.w) };
    *(bf16x4*)(h + i) = o;
}

__global__ __launch_bounds__(256) void k_cast_w(
    const float* __restrict__ qw, const float* __restrict__ pw,
    __bf16* __restrict__ qwb, __bf16* __restrict__ pwb)
{
    const int i = (blockIdx.x * 256 + threadIdx.x) * 4;
    const float* src; __bf16* dst; int off;
    if (i < 768 * 256) { src = qw; dst = qwb; off = i; }
    else               { src = pw; dst = pwb; off = i - 768 * 256; }
    float4 v = *(const float4*)(src + off);
    bf16x4 o = { (__bf16)v.x, (__bf16)v.y, (__bf16)v.z, (__bf16)v.w };
    *(bf16x4*)(dst + off) = o;
}

// ---------------------------------------------------------------------------
// bf16 MFMA GEMM: C[M][N] = A[M][256] @ B[N][256]^T (+bias), f32 out.
// 128x128 tile, BK=32, 256 threads = 4 waves (2x2 of 64x64), m97 recipe.
// ---------------------------------------------------------------------------
template<int N_, bool BIAS>
__global__ __launch_bounds__(256) void k_mfma_gemm(
    const __bf16* __restrict__ A, const __bf16* __restrict__ Bw,
    const float* __restrict__ bias, float* __restrict__ Cc)
{
    __shared__ __bf16 As[128 * 32];
    __shared__ __bf16 Bs[128 * 32];
    const int tid = threadIdx.x;
    const int wv = tid >> 6, ln = tid & 63;
    const int m0 = blockIdx.y * 128;
    const int n0 = blockIdx.x * 128;
    const int lr = ln >> 2;          // row within 16-row staging group
    const int lc = (ln & 3) * 8;     // bf16 col offset (0,8,16,24)
    const int wm = (wv >> 1) * 64;   // wave tile origin
    const int wn = (wv & 1) * 64;
    const int fr = ln & 15;          // fragment m / n index
    const int fk = (ln >> 4) * 8;    // fragment k offset

    f32x4 acc[4][4] = {};

    const __bf16* ga  = A  + (size_t)(m0 + wv * 16 + lr) * 256 + lc;
    const __bf16* gb  = Bw + (size_t)(n0 + wv * 16 + lr) * 256 + lc;

    for (int k0 = 0; k0 < 256; k0 += 32) {
        GLOAD_LDS16(ga + k0,            As + (wv * 16) * 32);
        GLOAD_LDS16(ga + k0 + 64 * 256, As + (64 + wv * 16) * 32);
        GLOAD_LDS16(gb + k0,            Bs + (wv * 16) * 32);
        GLOAD_LDS16(gb + k0 + 64 * 256, Bs + (64 + wv * 16) * 32);
        __syncthreads();

        bf16x8 af[4], bf[4];
#pragma unroll
        for (int i = 0; i < 4; ++i)
            af[i] = *(const bf16x8*)(As + (wm + i * 16 + fr) * 32 + fk);
#pragma unroll
        for (int j = 0; j < 4; ++j)
            bf[j] = *(const bf16x8*)(Bs + (wn + j * 16 + fr) * 32 + fk);
#pragma unroll
        for (int i = 0; i < 4; ++i)
#pragma unroll
            for (int j = 0; j < 4; ++j)
                acc[i][j] = __builtin_amdgcn_mfma_f32_16x16x32_bf16(
                    af[i], bf[j], acc[i][j], 0, 0, 0);
        __syncthreads();
    }

    const int cr = (ln >> 4) * 4;
    const int cc = ln & 15;
#pragma unroll
    for (int i = 0; i < 4; ++i)
#pragma unroll
        for (int j = 0; j < 4; ++j) {
            const int row = m0 + wm + i * 16 + cr;
            const int col = n0 + wn + j * 16 + cc;
            float* cp = Cc + (size_t)row * N_ + col;
            float bb = 0.f;
            if constexpr (BIAS) bb = bias[col];
#pragma unroll
            for (int r = 0; r < 4; ++r)
                cp[(size_t)r * N_] = acc[i][j][r] + bb;
        }
}

// ---------------------------------------------------------------------------
// RMS-norm q and k rows (D=32) in place. 8 rows / 256-thread block.
// ---------------------------------------------------------------------------
__global__ __launch_bounds__(256) void k_rmsnorm(
    float* __restrict__ qkv, const float* __restrict__ qg, const float* __restrict__ kg)
{
    const int rid  = blockIdx.x * 8 + (threadIdx.x >> 5);
    const int lane = threadIdx.x & 31;
    const int s    = rid >> 18;             // 0 = q, 1 = k
    const int rem  = rid & ((M_ * H_) - 1);
    const int m    = rem >> 3;
    const int h    = rem & 7;
    float* p = qkv + (size_t)m * 768 + s * 256 + h * 32;
    float v = p[lane];
    if (s == 0) v *= 0.17677669529663687f;   // D^{-1/2}
    float ss = v * v;
    ss += __shfl_xor(ss, 16);
    ss += __shfl_xor(ss, 8);
    ss += __shfl_xor(ss, 4);
    ss += __shfl_xor(ss, 2);
    ss += __shfl_xor(ss, 1);
    const float nrm = sqrtf(ss);
    const float g = (s == 0 ? qg : kg)[h * 32 + lane];
    p[lane] = v / fmaxf(nrm, 1e-12f) * 5.656854249492381f * g;  // * sqrt(D) * gamma
}

// ---------------------------------------------------------------------------
// Per-chunk KV outer product
// ---------------------------------------------------------------------------
__global__ __launch_bounds__(256) void k_chunk_kv(
    const float* __restrict__ qkv, float* __restrict__ kvbuf)
{
    __shared__ float ks[CHUNK_ * 32];
    __shared__ float vs[CHUNK_ * 32];
    const int blk = blockIdx.x;
    const int n  = blk & 31;
    const int bh = blk >> 5;
    const int h  = bh & 7;
    const int b  = bh >> 3;
    const float slope = exp2f(-(float)(h + 1));
    const int tid = threadIdx.x;
    const size_t rowbase = ((size_t)b * L_ + n * CHUNK_) * 768 + 256 + h * 32;
#pragma unroll
    for (int i = 0; i < 4; ++i) {
        int flat = i * 256 + tid;
        int pos  = flat >> 3;
        int quad = flat & 7;
        const float* kp = qkv + rowbase + (size_t)pos * 768 + quad * 4;
        float4 k4 = *(const float4*)kp;
        float4 v4 = *(const float4*)(kp + 256);
        float kd = __expf(-slope * (float)(CHUNK_ - pos));
        ks[pos * 32 + quad * 4 + 0] = k4.x * kd;
        ks[pos * 32 + quad * 4 + 1] = k4.y * kd;
        ks[pos * 32 + quad * 4 + 2] = k4.z * kd;
        ks[pos * 32 + quad * 4 + 3] = k4.w * kd;
        *(float4*)&vs[pos * 32 + quad * 4] = v4;
    }
    __syncthreads();
    const int e   = tid & 31;
    const int dd0 = tid >> 5;
    float acc[4] = {0.f, 0.f, 0.f, 0.f};
    for (int pos = 0; pos < CHUNK_; ++pos) {
        float vv = vs[pos * 32 + e];
        acc[0] += ks[pos * 32 + dd0 +  0] * vv;
        acc[1] += ks[pos * 32 + dd0 +  8] * vv;
        acc[2] += ks[pos * 32 + dd0 + 16] * vv;
        acc[3] += ks[pos * 32 + dd0 + 24] * vv;
    }
    float* out = kvbuf + (size_t)blk * 1024;
#pragma unroll
    for (int i = 0; i < 4; ++i) out[(dd0 + i * 8) * 32 + e] = acc[i];
}

// ---------------------------------------------------------------------------
// Chunk-state scan (exclusive prefix with decay)
// ---------------------------------------------------------------------------
__global__ __launch_bounds__(256) void k_scan(float* __restrict__ kvbuf)
{
    const int bh = blockIdx.x;
    const int tid = threadIdx.x;
    const float slope = exp2f(-(float)((bh & 7) + 1));
    const float bd = __expf(-slope * (float)CHUNK_);
    float4 st = {0.f, 0.f, 0.f, 0.f};
    float4* base = (float4*)(kvbuf + (size_t)bh * NC_ * 1024) + tid;
    for (int n = 0; n < NC_; ++n) {
        float4 tmp = base[n * 256];
        base[n * 256] = st;
        st.x = bd * st.x + tmp.x;
        st.y = bd * st.y + tmp.y;
        st.z = bd * st.z + tmp.z;
        st.w = bd * st.w + tmp.w;
    }
}

// ---------------------------------------------------------------------------
// Per-chunk output = intra (masked) + inter (q*qdecay @ kv_state), bf16 out.
// ---------------------------------------------------------------------------
__global__ __launch_bounds__(128) void k_attn_out(
    const float* __restrict__ qkv, const float* __restrict__ kvbuf,
    __bf16* __restrict__ attn_o)
{
    __shared__ float ks[CHUNK_ * 32];
    __shared__ float vs[CHUNK_ * 32];
    __shared__ float kvs[32 * 32];
    __shared__ float ejs[CHUNK_];
    const int blk = blockIdx.x;
    const int n  = blk & 31;
    const int bh = blk >> 5;
    const int h  = bh & 7;
    const int b  = bh >> 3;
    const float slope = exp2f(-(float)(h + 1));
    const int tid = threadIdx.x;   // row i, 0..127
    const size_t rowbase = ((size_t)b * L_ + n * CHUNK_) * 768 + h * 32;
#pragma unroll
    for (int i4 = 0; i4 < 8; ++i4) {
        int flat = i4 * 128 + tid;
        int pos  = flat >> 3;
        int quad = flat & 7;
        const float* kp = qkv + rowbase + (size_t)pos * 768 + 256 + quad * 4;
        *(float4*)&ks[pos * 32 + quad * 4] = *(const float4*)kp;
        *(float4*)&vs[pos * 32 + quad * 4] = *(const float4*)(kp + 256);
    }
    const float* kvp = kvbuf + (size_t)blk * 1024;
#pragma unroll
    for (int i = 0; i < 2; ++i)
        *(float4*)&kvs[i * 512 + tid * 4] = *(const float4*)&kvp[i * 512 + tid * 4];
    ejs[tid] = __expf(slope * (float)tid);
    __syncthreads();

    float q[32];
    const float* qp = qkv + rowbase + (size_t)tid * 768;
#pragma unroll
    for (int d4 = 0; d4 < 8; ++d4) *(float4*)&q[d4 * 4] = *(const float4*)(qp + d4 * 4);

    float o[32];
#pragma unroll
    for (int e = 0; e < 32; ++e) o[e] = 0.f;
    for (int d = 0; d < 32; ++d) {
        float coef = q[d];
#pragma unroll
        for (int e = 0; e < 32; ++e) o[e] += coef * kvs[d * 32 + e];
    }
    const float qdecay = __expf(-slope * (float)tid);
#pragma unroll
    for (int e = 0; e < 32; ++e) o[e] *= qdecay;
    for (int j = 0; j <= tid; ++j) {
        float dot = 0.f;
#pragma unroll
        for (int d = 0; d < 32; ++d) dot += q[d] * ks[j * 32 + d];
        float wgt = qdecay * ejs[j] * dot;
#pragma unroll
        for (int e = 0; e < 32; ++e) o[e] += wgt * vs[j * 32 + e];
    }
    __bf16* op = attn_o + ((size_t)b * L_ + n * CHUNK_ + tid) * C_ + h * 32;
#pragma unroll
    for (int e4 = 0; e4 < 8; ++e4) {
        bf16x4 o4 = { (__bf16)o[e4*4+0], (__bf16)o[e4*4+1],
                      (__bf16)o[e4*4+2], (__bf16)o[e4*4+3] };
        *(bf16x4*)(op + e4 * 4) = o4;
    }
}

// ---------------------------------------------------------------------------
extern "C" void kernel_launch(void* const* d_in, const int* in_sizes, int n_in,
                              void* d_out, int out_size, void* d_ws, size_t ws_size,
                              hipStream_t stream)
{
    const float* x     = (const float*)d_in[0];
    const float* rel   = (const float*)d_in[1];
    const float* qkv_w = (const float*)d_in[2];
    const float* qg    = (const float*)d_in[3];
    const float* kg    = (const float*)d_in[4];
    const float* pw    = (const float*)d_in[5];
    const float* pb    = (const float*)d_in[6];
    float* out = (float*)d_out;
    float* ws  = (float*)d_ws;

    float*  qkv   = ws;                                    // 25165824 f
    float*  kvb   = ws + (size_t)25165824;                 //  2097152 f
    __bf16* hb    = (__bf16*)(ws + (size_t)27262976);      //  8388608 bf16
    __bf16* attnb = (__bf16*)(ws + (size_t)31457280);      //  8388608 bf16
    __bf16* qwb   = (__bf16*)(ws + (size_t)35651584);      //   196608 bf16
    __bf16* pwb   = (__bf16*)(ws + (size_t)35749888);      //    65536 bf16

    k_cast_h<<<8192, 256, 0, stream>>>(x, rel, hb);
    k_cast_w<<<256, 256, 0, stream>>>(qkv_w, pw, qwb, pwb);
    k_mfma_gemm<768, false><<<dim3(6, 256), 256, 0, stream>>>(hb, qwb, nullptr, qkv);
    k_rmsnorm<<<65536, 256, 0, stream>>>(qkv, qg, kg);
    k_chunk_kv<<<2048, 256, 0, stream>>>(qkv, kvb);
    k_scan<<<64, 256, 0, stream>>>(kvb);
    k_attn_out<<<2048, 128, 0, stream>>>(qkv, kvb, attnb);
    k_mfma_gemm<256, true><<<dim3(2, 256), 256, 0, stream>>>(attnb, pwb, pb, out);
}

// Round 3
// 224.817 us; speedup vs baseline: 2.5775x; 1.3548x over previous
//
#include <hip/hip_runtime.h>
#include <hip/hip_bf16.h>

#define B_ 8
#define L_ 4096
#define C_ 256
#define H_ 8
#define D_ 32
#define CHUNK_ 128
#define NC_ 32
#define M_ (B_*L_)   // 32768

typedef _Float16 f16x8 __attribute__((ext_vector_type(8)));
typedef _Float16 f16x4 __attribute__((ext_vector_type(4)));
typedef float    f32x4 __attribute__((ext_vector_type(4)));

#define GLOAD_LDS16(g, l) __builtin_amdgcn_global_load_lds( \
    (const __attribute__((address_space(1))) unsigned int*)(g), \
    (__attribute__((address_space(3))) unsigned int*)(l), 16, 0, 0)

// ---------------------------------------------------------------------------
// h = f16(x + rel_pos)
// ---------------------------------------------------------------------------
__global__ __launch_bounds__(256) void k_cast_h(
    const float* __restrict__ x, const float* __restrict__ rel, _Float16* __restrict__ h)
{
    const int i = (blockIdx.x * 256 + threadIdx.x) * 4;
    float4 xv = *(const float4*)(x + i);
    float4 rv = *(const float4*)(rel + (i & (L_ * C_ - 1)));
    f16x4 o = { (_Float16)(xv.x + rv.x), (_Float16)(xv.y + rv.y),
                (_Float16)(xv.z + rv.z), (_Float16)(xv.w + rv.w) };
    *(f16x4*)(h + i) = o;
}

__global__ __launch_bounds__(256) void k_cast_w(
    const float* __restrict__ qw, const float* __restrict__ pw,
    _Float16* __restrict__ qwb, _Float16* __restrict__ pwb)
{
    const int i = (blockIdx.x * 256 + threadIdx.x) * 4;
    const float* src; _Float16* dst; int off;
    if (i < 768 * 256) { src = qw; dst = qwb; off = i; }
    else               { src = pw; dst = pwb; off = i - 768 * 256; }
    float4 v = *(const float4*)(src + off);
    f16x4 o = { (_Float16)v.x, (_Float16)v.y, (_Float16)v.z, (_Float16)v.w };
    *(f16x4*)(dst + off) = o;
}

// ---------------------------------------------------------------------------
// qkv GEMM (M=32768, N=768, K=256) -> packed f16 Qg/Kg [bh][l][32], Vtg [bh][e][4096]
// ---------------------------------------------------------------------------
__global__ __launch_bounds__(256) void k_qkv_gemm(
    const _Float16* __restrict__ A, const _Float16* __restrict__ Bw,
    _Float16* __restrict__ Qg, _Float16* __restrict__ Kg, _Float16* __restrict__ Vtg)
{
    __shared__ _Float16 As[128 * 32];
    __shared__ _Float16 Bs[128 * 32];
    const int tid = threadIdx.x;
    const int wv = tid >> 6, ln = tid & 63;
    const int m0 = blockIdx.y * 128;
    const int n0 = blockIdx.x * 128;
    const int lr = ln >> 2;
    const int lc = (ln & 3) * 8;
    const int wm = (wv >> 1) * 64;
    const int wn = (wv & 1) * 64;
    const int fr = ln & 15;
    const int fk = (ln >> 4) * 8;

    f32x4 acc[4][4] = {};
    const _Float16* ga = A  + (size_t)(m0 + wv * 16 + lr) * 256 + lc;
    const _Float16* gb = Bw + (size_t)(n0 + wv * 16 + lr) * 256 + lc;

    for (int k0 = 0; k0 < 256; k0 += 32) {
        GLOAD_LDS16(ga + k0,            As + (wv * 16) * 32);
        GLOAD_LDS16(ga + k0 + 64 * 256, As + (64 + wv * 16) * 32);
        GLOAD_LDS16(gb + k0,            Bs + (wv * 16) * 32);
        GLOAD_LDS16(gb + k0 + 64 * 256, Bs + (64 + wv * 16) * 32);
        __syncthreads();
        f16x8 af[4], bf[4];
#pragma unroll
        for (int i = 0; i < 4; ++i)
            af[i] = *(const f16x8*)(As + (wm + i * 16 + fr) * 32 + fk);
#pragma unroll
        for (int j = 0; j < 4; ++j)
            bf[j] = *(const f16x8*)(Bs + (wn + j * 16 + fr) * 32 + fk);
#pragma unroll
        for (int i = 0; i < 4; ++i)
#pragma unroll
            for (int j = 0; j < 4; ++j)
                acc[i][j] = __builtin_amdgcn_mfma_f32_16x16x32_f16(
                    af[i], bf[j], acc[i][j], 0, 0, 0);
        __syncthreads();
    }

    const int cr = (ln >> 4) * 4;
    const int cc = ln & 15;
    const int kind = n0 >> 8;                 // 0=q 1=k 2=v (128-tile within one kind)
    const int col0 = (n0 & 255) + wn;
    const int bb   = m0 >> 12;
    const int l00  = (m0 & 4095) + wm;

    if (kind < 2) {
        _Float16* P = kind ? Kg : Qg;
#pragma unroll
        for (int i = 0; i < 4; ++i)
#pragma unroll
            for (int j = 0; j < 4; ++j) {
                const int col = col0 + j * 16 + cc;
                const int hh = col >> 5, d = col & 31;
                const int l0 = l00 + i * 16 + cr;
                _Float16* p = P + ((size_t)(bb * 8 + hh) * 4096 + l0) * 32 + d;
#pragma unroll
                for (int r = 0; r < 4; ++r) p[r * 32] = (_Float16)acc[i][j][r];
            }
    } else {
#pragma unroll
        for (int i = 0; i < 4; ++i)
#pragma unroll
            for (int j = 0; j < 4; ++j) {
                const int col = col0 + j * 16 + cc;
                const int hh = col >> 5, e = col & 31;
                const int l0 = l00 + i * 16 + cr;
                f16x4 v4 = { (_Float16)acc[i][j][0], (_Float16)acc[i][j][1],
                             (_Float16)acc[i][j][2], (_Float16)acc[i][j][3] };
                *(f16x4*)(Vtg + ((size_t)(bb * 8 + hh) * 32 + e) * 4096 + l0) = v4;
            }
    }
}

// ---------------------------------------------------------------------------
// RMS-norm q,k rows (32 f16 each) in place on packed layout.
// ---------------------------------------------------------------------------
__global__ __launch_bounds__(256) void k_rmsnorm(
    _Float16* __restrict__ Qg, _Float16* __restrict__ Kg,
    const float* __restrict__ qg, const float* __restrict__ kg)
{
    const int rid  = blockIdx.x * 8 + (threadIdx.x >> 5);
    const int lane = threadIdx.x & 31;
    const int s    = rid >> 18;                // 0=q 1=k (262144 rows each)
    const int rem  = rid & 262143;             // (b*8+h)*4096 + l
    const int h    = (rem >> 12) & 7;
    _Float16* p = (s ? Kg : Qg) + (size_t)rem * 32;
    float v = (float)p[lane];
    if (s == 0) v *= 0.17677669529663687f;     // D^{-1/2}
    float ss = v * v;
    ss += __shfl_xor(ss, 16);
    ss += __shfl_xor(ss, 8);
    ss += __shfl_xor(ss, 4);
    ss += __shfl_xor(ss, 2);
    ss += __shfl_xor(ss, 1);
    const float nrm = sqrtf(ss);
    const float g = (s == 0 ? qg : kg)[h * 32 + lane];
    p[lane] = (_Float16)(v / fmaxf(nrm, 1e-12f) * 5.656854249492381f * g);
}

// ---------------------------------------------------------------------------
// Per-chunk KV outer product from packed f16 K, Vt.
// ---------------------------------------------------------------------------
__global__ __launch_bounds__(256) void k_chunk_kv(
    const _Float16* __restrict__ Kg, const _Float16* __restrict__ Vtg,
    float* __restrict__ kvbuf)
{
    __shared__ float ks[128 * 32];     // [pos][d]
    __shared__ float vst[32 * 129];    // [e][pos], stride 129 -> conflict-free inner
    const int blk = blockIdx.x;
    const int n  = blk & 31;
    const int bh = blk >> 5;
    const int h  = bh & 7;
    const float slope = exp2f(-(float)(h + 1));
    const float sl2 = slope * 1.44269504f;
    const int tid = threadIdx.x;
    const _Float16* Kc = Kg + ((size_t)bh * 4096 + n * CHUNK_) * 32;
#pragma unroll
    for (int i = 0; i < 2; ++i) {
        int flat = i * 256 + tid;          // 0..511 f16x8 groups
        int pos = flat >> 2;
        int d0  = (flat & 3) * 8;
        f16x8 k8 = *(const f16x8*)(Kc + flat * 8);
        float kd = exp2f(-sl2 * (float)(CHUNK_ - pos));
#pragma unroll
        for (int j = 0; j < 8; ++j) ks[pos * 32 + d0 + j] = (float)k8[j] * kd;
        int e = flat >> 4;
        int seg = flat & 15;
        f16x8 v8 = *(const f16x8*)(Vtg + ((size_t)bh * 32 + e) * 4096 + n * CHUNK_ + seg * 8);
#pragma unroll
        for (int j = 0; j < 8; ++j) vst[e * 129 + seg * 8 + j] = (float)v8[j];
    }
    __syncthreads();
    const int e   = tid & 31;
    const int dd0 = tid >> 5;
    float acc[4] = {0.f, 0.f, 0.f, 0.f};
    for (int pos = 0; pos < CHUNK_; ++pos) {
        float vv = vst[e * 129 + pos];
        acc[0] += ks[pos * 32 + dd0 +  0] * vv;
        acc[1] += ks[pos * 32 + dd0 +  8] * vv;
        acc[2] += ks[pos * 32 + dd0 + 16] * vv;
        acc[3] += ks[pos * 32 + dd0 + 24] * vv;
    }
    float* out = kvbuf + (size_t)blk * 1024;
#pragma unroll
    for (int i = 0; i < 4; ++i) out[(dd0 + i * 8) * 32 + e] = acc[i];
}

// ---------------------------------------------------------------------------
// Chunk-state scan (exclusive prefix with decay)
// ---------------------------------------------------------------------------
__global__ __launch_bounds__(256) void k_scan(float* __restrict__ kvbuf)
{
    const int bh = blockIdx.x;
    const int tid = threadIdx.x;
    const float slope = exp2f(-(float)((bh & 7) + 1));
    const float bd = __expf(-slope * (float)CHUNK_);
    float4 st = {0.f, 0.f, 0.f, 0.f};
    float4* base = (float4*)(kvbuf + (size_t)bh * NC_ * 1024) + tid;
    for (int n = 0; n < NC_; ++n) {
        float4 tmp = base[n * 256];
        base[n * 256] = st;
        st.x = bd * st.x + tmp.x;
        st.y = bd * st.y + tmp.y;
        st.z = bd * st.z + tmp.z;
        st.w = bd * st.w + tmp.w;
    }
}

// ---------------------------------------------------------------------------
// MFMA attention: per (b,h,chunk): S=Q K^T, mask, O = S̃ V + qd·(Q KV)
// 256 threads = 4 waves; wave w owns rows 32w..32w+31.
// ---------------------------------------------------------------------------
__global__ __launch_bounds__(256) void k_attn(
    const _Float16* __restrict__ Qg, const _Float16* __restrict__ Kg,
    const _Float16* __restrict__ Vtg, const float* __restrict__ kvbuf,
    _Float16* __restrict__ attnb)
{
    __shared__ _Float16 Qs[128 * 32];    // [i][d]
    __shared__ _Float16 Ks[128 * 32];    // [j][d]
    __shared__ _Float16 Vt[32 * 136];    // [e][j] pad
    __shared__ _Float16 KVt[32 * 40];    // [e][d] pad
    __shared__ _Float16 Ss[128 * 136];   // [i][j] pad
    const int blk = blockIdx.x;
    const int n  = blk & 31;
    const int bh = blk >> 5;
    const int h  = bh & 7;
    const int b  = bh >> 3;
    const float slope = exp2f(-(float)(h + 1));
    const float sl2 = slope * 1.44269504f;
    const int tid = threadIdx.x;
    const int wv = tid >> 6, ln = tid & 63;

    const _Float16* Qc = Qg + ((size_t)bh * 4096 + n * CHUNK_) * 32;
    const _Float16* Kc = Kg + ((size_t)bh * 4096 + n * CHUNK_) * 32;
#pragma unroll
    for (int i = 0; i < 2; ++i) {
        GLOAD_LDS16(Qc + (wv * 128 + i * 64 + ln) * 8, Qs + (wv * 128 + i * 64) * 8);
        GLOAD_LDS16(Kc + (wv * 128 + i * 64 + ln) * 8, Ks + (wv * 128 + i * 64) * 8);
    }
#pragma unroll
    for (int i = 0; i < 2; ++i) {
        int flat = i * 256 + tid;
        int e = flat >> 4, seg = flat & 15;
        f16x8 v8 = *(const f16x8*)(Vtg + ((size_t)bh * 32 + e) * 4096 + n * CHUNK_ + seg * 8);
        *(f16x8*)(Vt + e * 136 + seg * 8) = v8;
    }
    {
        int e = tid & 31, dg = tid >> 5;   // d0 = dg*4
        const float* kvp = kvbuf + (size_t)blk * 1024;
        f16x4 kv4 = { (_Float16)kvp[(dg * 4 + 0) * 32 + e],
                      (_Float16)kvp[(dg * 4 + 1) * 32 + e],
                      (_Float16)kvp[(dg * 4 + 2) * 32 + e],
                      (_Float16)kvp[(dg * 4 + 3) * 32 + e] };
        *(f16x4*)(KVt + e * 40 + dg * 4) = kv4;
    }
    __syncthreads();

    const int fr = ln & 15, fk = (ln >> 4) * 8;
    const int cr = (ln >> 4) * 4, cc = ln & 15;

    f16x8 aq[2];
#pragma unroll
    for (int i = 0; i < 2; ++i)
        aq[i] = *(const f16x8*)(Qs + (wv * 32 + i * 16 + fr) * 32 + fk);

    // S = Q K^T  (8 col tiles)
    f32x4 sacc[2][8] = {};
#pragma unroll
    for (int j = 0; j < 8; ++j) {
        f16x8 bk = *(const f16x8*)(Ks + (j * 16 + fr) * 32 + fk);
#pragma unroll
        for (int i = 0; i < 2; ++i)
            sacc[i][j] = __builtin_amdgcn_mfma_f32_16x16x32_f16(aq[i], bk, sacc[i][j], 0, 0, 0);
    }
    // inter: Q @ KV
    f32x4 iacc[2][2] = {};
#pragma unroll
    for (int ct = 0; ct < 2; ++ct) {
        f16x8 bkv = *(const f16x8*)(KVt + (ct * 16 + fr) * 40 + fk);
#pragma unroll
        for (int i = 0; i < 2; ++i)
            iacc[i][ct] = __builtin_amdgcn_mfma_f32_16x16x32_f16(aq[i], bkv, iacc[i][ct], 0, 0, 0);
    }
    // mask + write S̃ (f16) to LDS
#pragma unroll
    for (int i = 0; i < 2; ++i)
#pragma unroll
        for (int j = 0; j < 8; ++j)
#pragma unroll
            for (int r = 0; r < 4; ++r) {
                const int irow = wv * 32 + i * 16 + cr + r;
                const int jcol = j * 16 + cc;
                const float w = (jcol <= irow) ? exp2f(sl2 * (float)(jcol - irow)) : 0.f;
                Ss[irow * 136 + jcol] = (_Float16)(sacc[i][j][r] * w);
            }
    __syncthreads();

    // O_intra = S̃ @ V  (K=128 in 4 steps)
    f32x4 oacc[2][2] = {};
#pragma unroll
    for (int k = 0; k < 4; ++k) {
        f16x8 as[2], bv[2];
#pragma unroll
        for (int i = 0; i < 2; ++i)
            as[i] = *(const f16x8*)(Ss + (wv * 32 + i * 16 + fr) * 136 + k * 32 + fk);
#pragma unroll
        for (int ct = 0; ct < 2; ++ct)
            bv[ct] = *(const f16x8*)(Vt + (ct * 16 + fr) * 136 + k * 32 + fk);
#pragma unroll
        for (int i = 0; i < 2; ++i)
#pragma unroll
            for (int ct = 0; ct < 2; ++ct)
                oacc[i][ct] = __builtin_amdgcn_mfma_f32_16x16x32_f16(as[i], bv[ct], oacc[i][ct], 0, 0, 0);
    }
    // epilogue: out = oacc + qdecay(row) * iacc
#pragma unroll
    for (int i = 0; i < 2; ++i)
#pragma unroll
        for (int r = 0; r < 4; ++r) {
            const int irow = wv * 32 + i * 16 + cr + r;
            const float qd = exp2f(-sl2 * (float)irow);
            _Float16* op = attnb + ((size_t)b * 4096 + n * CHUNK_ + irow) * 256 + h * 32 + cc;
            op[0]  = (_Float16)(oacc[i][0][r] + qd * iacc[i][0][r]);
            op[16] = (_Float16)(oacc[i][1][r] + qd * iacc[i][1][r]);
        }
}

// ---------------------------------------------------------------------------
// proj GEMM: out = attn @ proj_w^T + b  (M=32768, N=256, K=256), f32 out.
// ---------------------------------------------------------------------------
__global__ __launch_bounds__(256) void k_proj_gemm(
    const _Float16* __restrict__ A, const _Float16* __restrict__ Bw,
    const float* __restrict__ bias, float* __restrict__ Cc)
{
    __shared__ _Float16 As[128 * 32];
    __shared__ _Float16 Bs[128 * 32];
    const int tid = threadIdx.x;
    const int wv = tid >> 6, ln = tid & 63;
    const int m0 = blockIdx.y * 128;
    const int n0 = blockIdx.x * 128;
    const int lr = ln >> 2;
    const int lc = (ln & 3) * 8;
    const int wm = (wv >> 1) * 64;
    const int wn = (wv & 1) * 64;
    const int fr = ln & 15;
    const int fk = (ln >> 4) * 8;

    f32x4 acc[4][4] = {};
    const _Float16* ga = A  + (size_t)(m0 + wv * 16 + lr) * 256 + lc;
    const _Float16* gb = Bw + (size_t)(n0 + wv * 16 + lr) * 256 + lc;

    for (int k0 = 0; k0 < 256; k0 += 32) {
        GLOAD_LDS16(ga + k0,            As + (wv * 16) * 32);
        GLOAD_LDS16(ga + k0 + 64 * 256, As + (64 + wv * 16) * 32);
        GLOAD_LDS16(gb + k0,            Bs + (wv * 16) * 32);
        GLOAD_LDS16(gb + k0 + 64 * 256, Bs + (64 + wv * 16) * 32);
        __syncthreads();
        f16x8 af[4], bf[4];
#pragma unroll
        for (int i = 0; i < 4; ++i)
            af[i] = *(const f16x8*)(As + (wm + i * 16 + fr) * 32 + fk);
#pragma unroll
        for (int j = 0; j < 4; ++j)
            bf[j] = *(const f16x8*)(Bs + (wn + j * 16 + fr) * 32 + fk);
#pragma unroll
        for (int i = 0; i < 4; ++i)
#pragma unroll
            for (int j = 0; j < 4; ++j)
                acc[i][j] = __builtin_amdgcn_mfma_f32_16x16x32_f16(
                    af[i], bf[j], acc[i][j], 0, 0, 0);
        __syncthreads();
    }
    const int cr = (ln >> 4) * 4;
    const int cc = ln & 15;
#pragma unroll
    for (int i = 0; i < 4; ++i)
#pragma unroll
        for (int j = 0; j < 4; ++j) {
            const int row = m0 + wm + i * 16 + cr;
            const int col = n0 + wn + j * 16 + cc;
            float* cp = Cc + (size_t)row * 256 + col;
            const float bb = bias[col];
#pragma unroll
            for (int r = 0; r < 4; ++r) cp[(size_t)r * 256] = acc[i][j][r] + bb;
        }
}

// ---------------------------------------------------------------------------
extern "C" void kernel_launch(void* const* d_in, const int* in_sizes, int n_in,
                              void* d_out, int out_size, void* d_ws, size_t ws_size,
                              hipStream_t stream)
{
    const float* x     = (const float*)d_in[0];
    const float* rel   = (const float*)d_in[1];
    const float* qkv_w = (const float*)d_in[2];
    const float* qg    = (const float*)d_in[3];
    const float* kg    = (const float*)d_in[4];
    const float* pw    = (const float*)d_in[5];
    const float* pb    = (const float*)d_in[6];
    float* out = (float*)d_out;
    char* wsb = (char*)d_ws;

    float*    kvb   = (float*)wsb;                            // 8 MB
    _Float16* hb    = (_Float16*)(wsb + ((size_t)8  << 20));  // 16 MB
    _Float16* Qg    = (_Float16*)(wsb + ((size_t)24 << 20));  // 16 MB
    _Float16* Kg    = (_Float16*)(wsb + ((size_t)40 << 20));  // 16 MB
    _Float16* Vtg   = (_Float16*)(wsb + ((size_t)56 << 20));  // 16 MB
    _Float16* attnb = (_Float16*)(wsb + ((size_t)72 << 20));  // 16 MB
    _Float16* qwb   = (_Float16*)(wsb + ((size_t)88 << 20));  // 384 KB
    _Float16* pwb   = (_Float16*)(wsb + ((size_t)89 << 20));  // 128 KB

    k_cast_h<<<8192, 256, 0, stream>>>(x, rel, hb);
    k_cast_w<<<256, 256, 0, stream>>>(qkv_w, pw, qwb, pwb);
    k_qkv_gemm<<<dim3(6, 256), 256, 0, stream>>>(hb, qwb, Qg, Kg, Vtg);
    k_rmsnorm<<<65536, 256, 0, stream>>>(Qg, Kg, qg, kg);
    k_chunk_kv<<<2048, 256, 0, stream>>>(Kg, Vtg, kvb);
    k_scan<<<64, 256, 0, stream>>>(kvb);
    k_attn<<<2048, 256, 0, stream>>>(Qg, Kg, Vtg, kvb, attnb);
    k_proj_gemm<<<dim3(2, 256), 256, 0, stream>>>(attnb, pwb, pb, out);
}

// Round 4
// 204.940 us; speedup vs baseline: 2.8275x; 1.0970x over previous
//
#include <hip/hip_runtime.h>
#include <hip/hip_bf16.h>

#define B_ 8
#define L_ 4096
#define C_ 256
#define H_ 8
#define D_ 32
#define CHUNK_ 128
#define NC_ 32
#define M_ (B_*L_)   // 32768

typedef _Float16 f16x8 __attribute__((ext_vector_type(8)));
typedef _Float16 f16x4 __attribute__((ext_vector_type(4)));
typedef float    f32x4 __attribute__((ext_vector_type(4)));

#define GLOAD_LDS16(g, l) __builtin_amdgcn_global_load_lds( \
    (const __attribute__((address_space(1))) unsigned int*)(g), \
    (__attribute__((address_space(3))) unsigned int*)(l), 16, 0, 0)

// ---------------------------------------------------------------------------
// Weights -> f16
// ---------------------------------------------------------------------------
__global__ __launch_bounds__(256) void k_cast_w(
    const float* __restrict__ qw, const float* __restrict__ pw,
    _Float16* __restrict__ qwb, _Float16* __restrict__ pwb)
{
    const int i = (blockIdx.x * 256 + threadIdx.x) * 4;
    const float* src; _Float16* dst; int off;
    if (i < 768 * 256) { src = qw; dst = qwb; off = i; }
    else               { src = pw; dst = pwb; off = i - 768 * 256; }
    float4 v = *(const float4*)(src + off);
    f16x4 o = { (_Float16)v.x, (_Float16)v.y, (_Float16)v.z, (_Float16)v.w };
    *(f16x4*)(dst + off) = o;
}

// ---------------------------------------------------------------------------
// Fused qkv GEMM: A = f16(x+rel) staged in-kernel; epilogue fuses RMS-norm
// for Q/K and writes packed layouts:
//   Qg/Kg [bh][l][32] (normed), Vtg [bh][e][4096] (transposed).
// Grid (6, 256): bx 0,1=Q  2,3=K  4,5=V.
// ---------------------------------------------------------------------------
__global__ __launch_bounds__(256) void k_qkv_fused(
    const float* __restrict__ x, const float* __restrict__ rel,
    const _Float16* __restrict__ Bw,
    const float* __restrict__ qg, const float* __restrict__ kg,
    _Float16* __restrict__ Qg, _Float16* __restrict__ Kg, _Float16* __restrict__ Vtg)
{
    __shared__ _Float16 As[128 * 32];
    __shared__ _Float16 Bs[128 * 32];
    __shared__ _Float16 Ws[128 * 132];   // Q/K output staging, stride 132 (bank-safe)
    const int tid = threadIdx.x;
    const int wv = tid >> 6, ln = tid & 63;
    const int m0 = blockIdx.y * 128;
    const int n0 = blockIdx.x * 128;
    const int lr = ln >> 2;
    const int lc = (ln & 3) * 8;
    const int wm = (wv >> 1) * 64;
    const int wn = (wv & 1) * 64;
    const int fr = ln & 15;
    const int fk = (ln >> 4) * 8;

    f32x4 acc[4][4] = {};
    const _Float16* gb = Bw + (size_t)(n0 + wv * 16 + lr) * 256 + lc;

    for (int k0 = 0; k0 < 256; k0 += 32) {
        GLOAD_LDS16(gb + k0,            Bs + (wv * 16) * 32);
        GLOAD_LDS16(gb + k0 + 64 * 256, Bs + (64 + wv * 16) * 32);
        // A staging: f32 x + rel -> f16 LDS (cast fused)
#pragma unroll
        for (int t = 0; t < 4; ++t) {
            const int flat = t * 256 + tid;
            const int row = flat >> 3;
            const int c4  = (flat & 7) * 4;
            const float* xp = x   + (size_t)(m0 + row) * 256 + k0 + c4;
            const float* rp = rel + (size_t)((m0 + row) & 4095) * 256 + k0 + c4;
            float4 xv = *(const float4*)xp;
            float4 rv = *(const float4*)rp;
            f16x4 hv = { (_Float16)(xv.x + rv.x), (_Float16)(xv.y + rv.y),
                         (_Float16)(xv.z + rv.z), (_Float16)(xv.w + rv.w) };
            *(f16x4*)(As + row * 32 + c4) = hv;
        }
        __syncthreads();
        f16x8 af[4], bf[4];
#pragma unroll
        for (int i = 0; i < 4; ++i)
            af[i] = *(const f16x8*)(As + (wm + i * 16 + fr) * 32 + fk);
#pragma unroll
        for (int j = 0; j < 4; ++j)
            bf[j] = *(const f16x8*)(Bs + (wn + j * 16 + fr) * 32 + fk);
#pragma unroll
        for (int i = 0; i < 4; ++i)
#pragma unroll
            for (int j = 0; j < 4; ++j)
                acc[i][j] = __builtin_amdgcn_mfma_f32_16x16x32_f16(
                    af[i], bf[j], acc[i][j], 0, 0, 0);
        __syncthreads();
    }

    const int cr = (ln >> 4) * 4;
    const int cc = ln & 15;
    const int kind = n0 >> 8;                 // 0=q 1=k 2=v
    const int col0 = (n0 & 255) + wn;
    const int bb   = m0 >> 12;
    const int l00  = m0 & 4095;

    if (kind < 2) {
        // fused RMS-norm: each head = 32 cols = 2 j-tiles x 16 lanes
        const float* gsrc = kind ? kg : qg;
        float gma[2][2];
#pragma unroll
        for (int jp = 0; jp < 2; ++jp)
#pragma unroll
            for (int jj = 0; jj < 2; ++jj)
                gma[jp][jj] = gsrc[((col0 >> 5) + jp) * 32 + jj * 16 + cc];
#pragma unroll
        for (int i = 0; i < 4; ++i)
#pragma unroll
            for (int r = 0; r < 4; ++r) {
                const int irow = wm + i * 16 + cr + r;
#pragma unroll
                for (int jp = 0; jp < 2; ++jp) {
                    const float a0 = acc[i][jp * 2][r];
                    const float a1 = acc[i][jp * 2 + 1][r];
                    float ss = a0 * a0 + a1 * a1;
                    ss += __shfl_xor(ss, 1);
                    ss += __shfl_xor(ss, 2);
                    ss += __shfl_xor(ss, 4);
                    ss += __shfl_xor(ss, 8);
                    // q's D^-1/2 pre-scale cancels in t/||t|| (scale-invariant)
                    const float sc = 5.656854249492381f / fmaxf(sqrtf(ss), 1e-12f);
                    Ws[irow * 132 + wn + jp * 32 + cc]      = (_Float16)(a0 * sc * gma[jp][0]);
                    Ws[irow * 132 + wn + jp * 32 + 16 + cc] = (_Float16)(a1 * sc * gma[jp][1]);
                }
            }
        __syncthreads();
        _Float16* P = kind ? Kg : Qg;
        const int hbase = (n0 & 255) >> 5;
#pragma unroll
        for (int kk = 0; kk < 8; ++kk) {
            const int c = kk * 256 + tid;
            const int hh = c >> 9;
            const int rr = (c >> 2) & 127;
            const int part = (c & 3) * 8;
            f16x8 v8 = *(const f16x8*)(Ws + rr * 132 + hh * 32 + part);
            *(f16x8*)(P + ((size_t)(bb * 8 + hbase + hh) * 4096 + l00 + rr) * 32 + part) = v8;
        }
    } else {
        // V: transposed store Vtg[bh*32+e][l], f16x4 over the 4 acc rows
#pragma unroll
        for (int i = 0; i < 4; ++i)
#pragma unroll
            for (int j = 0; j < 4; ++j) {
                const int col = col0 + j * 16 + cc;
                const int hh = col >> 5, e = col & 31;
                const int l0 = l00 + wm + i * 16 + cr;
                f16x4 v4 = { (_Float16)acc[i][j][0], (_Float16)acc[i][j][1],
                             (_Float16)acc[i][j][2], (_Float16)acc[i][j][3] };
                *(f16x4*)(Vtg + ((size_t)(bb * 8 + hh) * 32 + e) * 4096 + l0) = v4;
            }
    }
}

// ---------------------------------------------------------------------------
// Per-chunk KV outer product from packed f16 K, Vt.
// ---------------------------------------------------------------------------
__global__ __launch_bounds__(256) void k_chunk_kv(
    const _Float16* __restrict__ Kg, const _Float16* __restrict__ Vtg,
    float* __restrict__ kvbuf)
{
    __shared__ float ks[128 * 32];     // [pos][d]
    __shared__ float vst[32 * 129];    // [e][pos]
    const int blk = blockIdx.x;
    const int n  = blk & 31;
    const int bh = blk >> 5;
    const int h  = bh & 7;
    const float slope = exp2f(-(float)(h + 1));
    const float sl2 = slope * 1.44269504f;
    const int tid = threadIdx.x;
    const _Float16* Kc = Kg + ((size_t)bh * 4096 + n * CHUNK_) * 32;
#pragma unroll
    for (int i = 0; i < 2; ++i) {
        int flat = i * 256 + tid;
        int pos = flat >> 2;
        int d0  = (flat & 3) * 8;
        f16x8 k8 = *(const f16x8*)(Kc + flat * 8);
        float kd = exp2f(-sl2 * (float)(CHUNK_ - pos));
#pragma unroll
        for (int j = 0; j < 8; ++j) ks[pos * 32 + d0 + j] = (float)k8[j] * kd;
        int e = flat >> 4;
        int seg = flat & 15;
        f16x8 v8 = *(const f16x8*)(Vtg + ((size_t)bh * 32 + e) * 4096 + n * CHUNK_ + seg * 8);
#pragma unroll
        for (int j = 0; j < 8; ++j) vst[e * 129 + seg * 8 + j] = (float)v8[j];
    }
    __syncthreads();
    const int e   = tid & 31;
    const int dd0 = tid >> 5;
    float acc[4] = {0.f, 0.f, 0.f, 0.f};
    for (int pos = 0; pos < CHUNK_; ++pos) {
        float vv = vst[e * 129 + pos];
        acc[0] += ks[pos * 32 + dd0 +  0] * vv;
        acc[1] += ks[pos * 32 + dd0 +  8] * vv;
        acc[2] += ks[pos * 32 + dd0 + 16] * vv;
        acc[3] += ks[pos * 32 + dd0 + 24] * vv;
    }
    float* out = kvbuf + (size_t)blk * 1024;
#pragma unroll
    for (int i = 0; i < 4; ++i) out[(dd0 + i * 8) * 32 + e] = acc[i];
}

// ---------------------------------------------------------------------------
// Chunk-state scan, batched prefetch to hide latency.
// ---------------------------------------------------------------------------
__global__ __launch_bounds__(256) void k_scan(float* __restrict__ kvbuf)
{
    const int bh = blockIdx.x;
    const int tid = threadIdx.x;
    const float slope = exp2f(-(float)((bh & 7) + 1));
    const float bd = __expf(-slope * (float)CHUNK_);
    float4 st = {0.f, 0.f, 0.f, 0.f};
    float4* base = (float4*)(kvbuf + (size_t)bh * NC_ * 1024) + tid;
#pragma unroll
    for (int g = 0; g < 4; ++g) {
        float4 tmp[8];
#pragma unroll
        for (int k = 0; k < 8; ++k) tmp[k] = base[(g * 8 + k) * 256];
#pragma unroll
        for (int k = 0; k < 8; ++k) {
            base[(g * 8 + k) * 256] = st;
            st.x = bd * st.x + tmp[k].x;
            st.y = bd * st.y + tmp[k].y;
            st.z = bd * st.z + tmp[k].z;
            st.w = bd * st.w + tmp[k].w;
        }
    }
}

// ---------------------------------------------------------------------------
// MFMA attention per (b,h,chunk): S=Q K^T, decay-mask, O = S̃ V + qd·(Q KV).
// Output written packed [bh][l][32] via LDS (one contiguous 8 KB burst).
// ---------------------------------------------------------------------------
__global__ __launch_bounds__(256) void k_attn(
    const _Float16* __restrict__ Qg, const _Float16* __restrict__ Kg,
    const _Float16* __restrict__ Vtg, const float* __restrict__ kvbuf,
    _Float16* __restrict__ attnp)
{
    __shared__ _Float16 Qs[128 * 32];
    __shared__ _Float16 Ks[128 * 32];
    __shared__ _Float16 Vt[32 * 136];
    __shared__ _Float16 KVt[32 * 40];
    __shared__ _Float16 Ss[128 * 136];
    __shared__ _Float16 Os[128 * 36];
    __shared__ float ejs[CHUNK_];
    const int blk = blockIdx.x;
    const int n  = blk & 31;
    const int bh = blk >> 5;
    const int h  = bh & 7;
    const float slope = exp2f(-(float)(h + 1));
    const float sl2 = slope * 1.44269504f;
    const int tid = threadIdx.x;
    const int wv = tid >> 6, ln = tid & 63;

    const _Float16* Qc = Qg + ((size_t)bh * 4096 + n * CHUNK_) * 32;
    const _Float16* Kc = Kg + ((size_t)bh * 4096 + n * CHUNK_) * 32;
#pragma unroll
    for (int i = 0; i < 2; ++i) {
        GLOAD_LDS16(Qc + (wv * 128 + i * 64 + ln) * 8, Qs + (wv * 128 + i * 64) * 8);
        GLOAD_LDS16(Kc + (wv * 128 + i * 64 + ln) * 8, Ks + (wv * 128 + i * 64) * 8);
    }
#pragma unroll
    for (int i = 0; i < 2; ++i) {
        int flat = i * 256 + tid;
        int e = flat >> 4, seg = flat & 15;
        f16x8 v8 = *(const f16x8*)(Vtg + ((size_t)bh * 32 + e) * 4096 + n * CHUNK_ + seg * 8);
        *(f16x8*)(Vt + e * 136 + seg * 8) = v8;
    }
    {
        int e = tid & 31, dg = tid >> 5;
        const float* kvp = kvbuf + (size_t)blk * 1024;
        f16x4 kv4 = { (_Float16)kvp[(dg * 4 + 0) * 32 + e],
                      (_Float16)kvp[(dg * 4 + 1) * 32 + e],
                      (_Float16)kvp[(dg * 4 + 2) * 32 + e],
                      (_Float16)kvp[(dg * 4 + 3) * 32 + e] };
        *(f16x4*)(KVt + e * 40 + dg * 4) = kv4;
    }
    if (tid < CHUNK_) ejs[tid] = exp2f(sl2 * (float)tid);
    __syncthreads();

    const int fr = ln & 15, fk = (ln >> 4) * 8;
    const int cr = (ln >> 4) * 4, cc = ln & 15;

    f16x8 aq[2];
#pragma unroll
    for (int i = 0; i < 2; ++i)
        aq[i] = *(const f16x8*)(Qs + (wv * 32 + i * 16 + fr) * 32 + fk);

    f32x4 sacc[2][8] = {};
#pragma unroll
    for (int j = 0; j < 8; ++j) {
        f16x8 bk = *(const f16x8*)(Ks + (j * 16 + fr) * 32 + fk);
#pragma unroll
        for (int i = 0; i < 2; ++i)
            sacc[i][j] = __builtin_amdgcn_mfma_f32_16x16x32_f16(aq[i], bk, sacc[i][j], 0, 0, 0);
    }
    f32x4 iacc[2][2] = {};
#pragma unroll
    for (int ct = 0; ct < 2; ++ct) {
        f16x8 bkv = *(const f16x8*)(KVt + (ct * 16 + fr) * 40 + fk);
#pragma unroll
        for (int i = 0; i < 2; ++i)
            iacc[i][ct] = __builtin_amdgcn_mfma_f32_16x16x32_f16(aq[i], bkv, iacc[i][ct], 0, 0, 0);
    }
    // decay mask: w = ejs[jcol] * exp2(-sl2*irow)  (<= 1, factorized)
    float ejr[8];
#pragma unroll
    for (int j = 0; j < 8; ++j) ejr[j] = ejs[j * 16 + cc];
    const float c1 = exp2f(-sl2);
    float qd_save[2][4];
#pragma unroll
    for (int i = 0; i < 2; ++i) {
        float er = exp2f(-sl2 * (float)(wv * 32 + i * 16 + cr));
#pragma unroll
        for (int r = 0; r < 4; ++r) {
            const int irow = wv * 32 + i * 16 + cr + r;
            qd_save[i][r] = er;
#pragma unroll
            for (int j = 0; j < 8; ++j) {
                const int jcol = j * 16 + cc;
                const float w = (jcol <= irow) ? ejr[j] * er : 0.f;
                Ss[irow * 136 + jcol] = (_Float16)(sacc[i][j][r] * w);
            }
            er *= c1;
        }
    }
    __syncthreads();

    f32x4 oacc[2][2] = {};
#pragma unroll
    for (int k = 0; k < 4; ++k) {
        f16x8 as[2], bv[2];
#pragma unroll
        for (int i = 0; i < 2; ++i)
            as[i] = *(const f16x8*)(Ss + (wv * 32 + i * 16 + fr) * 136 + k * 32 + fk);
#pragma unroll
        for (int ct = 0; ct < 2; ++ct)
            bv[ct] = *(const f16x8*)(Vt + (ct * 16 + fr) * 136 + k * 32 + fk);
#pragma unroll
        for (int i = 0; i < 2; ++i)
#pragma unroll
            for (int ct = 0; ct < 2; ++ct)
                oacc[i][ct] = __builtin_amdgcn_mfma_f32_16x16x32_f16(as[i], bv[ct], oacc[i][ct], 0, 0, 0);
    }
    // epilogue -> LDS -> one contiguous coalesced burst
#pragma unroll
    for (int i = 0; i < 2; ++i)
#pragma unroll
        for (int r = 0; r < 4; ++r) {
            const int irow = wv * 32 + i * 16 + cr + r;
            const float qd = qd_save[i][r];
            Os[irow * 36 + cc]      = (_Float16)(oacc[i][0][r] + qd * iacc[i][0][r]);
            Os[irow * 36 + 16 + cc] = (_Float16)(oacc[i][1][r] + qd * iacc[i][1][r]);
        }
    __syncthreads();
    _Float16* abase = attnp + ((size_t)bh * 4096 + n * CHUNK_) * 32;
#pragma unroll
    for (int kk = 0; kk < 2; ++kk) {
        const int c = kk * 256 + tid;
        const int rr = c >> 2;
        const int part = (c & 3) * 8;
        *(f16x8*)(abase + rr * 32 + part) = *(const f16x8*)(Os + rr * 36 + part);
    }
}

// ---------------------------------------------------------------------------
// proj GEMM: out = attn @ proj_w^T + b, A read from packed [bh][l][32]
// (k-step of 32 == exactly one head).
// ---------------------------------------------------------------------------
__global__ __launch_bounds__(256) void k_proj_gemm(
    const _Float16* __restrict__ attnp, const _Float16* __restrict__ Bw,
    const float* __restrict__ bias, float* __restrict__ Cc)
{
    __shared__ _Float16 As[128 * 32];
    __shared__ _Float16 Bs[128 * 32];
    const int tid = threadIdx.x;
    const int wv = tid >> 6, ln = tid & 63;
    const int m0 = blockIdx.y * 128;
    const int n0 = blockIdx.x * 128;
    const int lr = ln >> 2;
    const int lc = (ln & 3) * 8;
    const int wm = (wv >> 1) * 64;
    const int wn = (wv & 1) * 64;
    const int fr = ln & 15;
    const int fk = (ln >> 4) * 8;

    f32x4 acc[4][4] = {};
    const int gmrow = m0 + wv * 16 + lr;
    const _Float16* ga = attnp +
        ((size_t)(gmrow >> 12) * 8 * 4096 + (gmrow & 4095)) * 32 + lc;
    const _Float16* gb = Bw + (size_t)(n0 + wv * 16 + lr) * 256 + lc;

    for (int k0 = 0; k0 < 256; k0 += 32) {
        const size_t hoff = (size_t)(k0 >> 5) * (4096 * 32);
        GLOAD_LDS16(ga + hoff,           As + (wv * 16) * 32);
        GLOAD_LDS16(ga + hoff + 64 * 32, As + (64 + wv * 16) * 32);
        GLOAD_LDS16(gb + k0,             Bs + (wv * 16) * 32);
        GLOAD_LDS16(gb + k0 + 64 * 256,  Bs + (64 + wv * 16) * 32);
        __syncthreads();
        f16x8 af[4], bf[4];
#pragma unroll
        for (int i = 0; i < 4; ++i)
            af[i] = *(const f16x8*)(As + (wm + i * 16 + fr) * 32 + fk);
#pragma unroll
        for (int j = 0; j < 4; ++j)
            bf[j] = *(const f16x8*)(Bs + (wn + j * 16 + fr) * 32 + fk);
#pragma unroll
        for (int i = 0; i < 4; ++i)
#pragma unroll
            for (int j = 0; j < 4; ++j)
                acc[i][j] = __builtin_amdgcn_mfma_f32_16x16x32_f16(
                    af[i], bf[j], acc[i][j], 0, 0, 0);
        __syncthreads();
    }
    const int cr = (ln >> 4) * 4;
    const int cc = ln & 15;
#pragma unroll
    for (int i = 0; i < 4; ++i)
#pragma unroll
        for (int j = 0; j < 4; ++j) {
            const int row = m0 + wm + i * 16 + cr;
            const int col = n0 + wn + j * 16 + cc;
            float* cp = Cc + (size_t)row * 256 + col;
            const float bb = bias[col];
#pragma unroll
            for (int r = 0; r < 4; ++r) cp[(size_t)r * 256] = acc[i][j][r] + bb;
        }
}

// ---------------------------------------------------------------------------
extern "C" void kernel_launch(void* const* d_in, const int* in_sizes, int n_in,
                              void* d_out, int out_size, void* d_ws, size_t ws_size,
                              hipStream_t stream)
{
    const float* x     = (const float*)d_in[0];
    const float* rel   = (const float*)d_in[1];
    const float* qkv_w = (const float*)d_in[2];
    const float* qg    = (const float*)d_in[3];
    const float* kg    = (const float*)d_in[4];
    const float* pw    = (const float*)d_in[5];
    const float* pb    = (const float*)d_in[6];
    float* out = (float*)d_out;
    char* wsb = (char*)d_ws;

    float*    kvb   = (float*)wsb;                            // 8 MB
    _Float16* Qg    = (_Float16*)(wsb + ((size_t)8  << 20));  // 16 MB
    _Float16* Kg    = (_Float16*)(wsb + ((size_t)24 << 20));  // 16 MB
    _Float16* Vtg   = (_Float16*)(wsb + ((size_t)40 << 20));  // 16 MB
    _Float16* attnp = (_Float16*)(wsb + ((size_t)56 << 20));  // 16 MB
    _Float16* qwb   = (_Float16*)(wsb + ((size_t)72 << 20));  // 384 KB
    _Float16* pwb   = (_Float16*)(wsb + ((size_t)73 << 20));  // 128 KB

    k_cast_w<<<256, 256, 0, stream>>>(qkv_w, pw, qwb, pwb);
    k_qkv_fused<<<dim3(6, 256), 256, 0, stream>>>(x, rel, qwb, qg, kg, Qg, Kg, Vtg);
    k_chunk_kv<<<2048, 256, 0, stream>>>(Kg, Vtg, kvb);
    k_scan<<<64, 256, 0, stream>>>(kvb);
    k_attn<<<2048, 256, 0, stream>>>(Qg, Kg, Vtg, kvb, attnp);
    k_proj_gemm<<<dim3(2, 256), 256, 0, stream>>>(attnp, pwb, pb, out);
}

// Round 5
// 203.377 us; speedup vs baseline: 2.8492x; 1.0077x over previous
//
#include <hip/hip_runtime.h>
#include <hip/hip_bf16.h>

#define B_ 8
#define L_ 4096
#define C_ 256
#define H_ 8
#define D_ 32
#define CHUNK_ 128
#define NC_ 32
#define M_ (B_*L_)   // 32768

typedef _Float16 f16x8 __attribute__((ext_vector_type(8)));
typedef _Float16 f16x4 __attribute__((ext_vector_type(4)));
typedef float    f32x4 __attribute__((ext_vector_type(4)));

#define GLOAD_LDS16(g, l) __builtin_amdgcn_global_load_lds( \
    (const __attribute__((address_space(1))) unsigned int*)(g), \
    (__attribute__((address_space(3))) unsigned int*)(l), 16, 0, 0)

// ---------------------------------------------------------------------------
// Weights -> f16
// ---------------------------------------------------------------------------
__global__ __launch_bounds__(256) void k_cast_w(
    const float* __restrict__ qw, const float* __restrict__ pw,
    _Float16* __restrict__ qwb, _Float16* __restrict__ pwb)
{
    const int i = (blockIdx.x * 256 + threadIdx.x) * 4;
    const float* src; _Float16* dst; int off;
    if (i < 768 * 256) { src = qw; dst = qwb; off = i; }
    else               { src = pw; dst = pwb; off = i - 768 * 256; }
    float4 v = *(const float4*)(src + off);
    f16x4 o = { (_Float16)v.x, (_Float16)v.y, (_Float16)v.z, (_Float16)v.w };
    *(f16x4*)(dst + off) = o;
}

// ---------------------------------------------------------------------------
// Fused qkv GEMM, grid (3, 256): bx = kind (0=Q 1=K 2=V), 128 M-rows x 256 N.
// 512 threads = 8 waves (4 wave-rows x 2 wave-cols), each wave 32x128, acc[2][8].
// A = f16(x+rel) cast in staging (runs 3x total, not 6x). Epilogue fuses
// RMS-norm for Q/K (head = 2 j-tiles, 16-lane shfl reduce) -> packed
// Qg/Kg [bh][l][32]; V -> transposed Vtg [bh][e][4096].
// ---------------------------------------------------------------------------
__global__ __launch_bounds__(512) void k_qkv_fused(
    const float* __restrict__ x, const float* __restrict__ rel,
    const _Float16* __restrict__ Bw,
    const float* __restrict__ qg, const float* __restrict__ kg,
    _Float16* __restrict__ Qg, _Float16* __restrict__ Kg, _Float16* __restrict__ Vtg)
{
    __shared__ __align__(16) char smem[24576];        // As(8K)+Bs(16K); Ws reuses
    _Float16* As = (_Float16*)smem;                   // [128][32]
    _Float16* Bs = As + 128 * 32;                     // [256][32]
    _Float16* Ws = (_Float16*)smem;                   // [128][72] (post-loop reuse)

    const int tid = threadIdx.x;
    const int wv = tid >> 6, ln = tid & 63;
    const int kind = blockIdx.x;                      // 0=Q 1=K 2=V
    const int m0 = blockIdx.y * 128;
    const int wr = wv >> 1, wc = wv & 1;              // wave row/col
    const int lr = ln >> 2, lc = (ln & 3) * 8;
    const int fr = ln & 15, fk = (ln >> 4) * 8;

    const int arow = tid >> 2;                        // 0..127
    const int aseg = (tid & 3) * 8;                   // 0,8,16,24
    const float* xp = x   + (size_t)(m0 + arow) * 256 + aseg;
    const float* rp = rel + (size_t)((m0 + arow) & 4095) * 256 + aseg;
    const _Float16* gb = Bw + (size_t)(kind * 256 + wv * 16 + lr) * 256 + lc;

    f32x4 acc[2][8] = {};
    for (int k0 = 0; k0 < 256; k0 += 32) {
        GLOAD_LDS16(gb + k0,             Bs + (wv * 16) * 32);
        GLOAD_LDS16(gb + k0 + 128 * 256, Bs + (128 + wv * 16) * 32);
        float4 x0 = *(const float4*)(xp + k0);
        float4 x1 = *(const float4*)(xp + k0 + 4);
        float4 r0 = *(const float4*)(rp + k0);
        float4 r1 = *(const float4*)(rp + k0 + 4);
        f16x8 hv = { (_Float16)(x0.x + r0.x), (_Float16)(x0.y + r0.y),
                     (_Float16)(x0.z + r0.z), (_Float16)(x0.w + r0.w),
                     (_Float16)(x1.x + r1.x), (_Float16)(x1.y + r1.y),
                     (_Float16)(x1.z + r1.z), (_Float16)(x1.w + r1.w) };
        *(f16x8*)(As + arow * 32 + aseg) = hv;
        __syncthreads();
        f16x8 af[2], bf[8];
#pragma unroll
        for (int i = 0; i < 2; ++i)
            af[i] = *(const f16x8*)(As + (wr * 32 + i * 16 + fr) * 32 + fk);
#pragma unroll
        for (int j = 0; j < 8; ++j)
            bf[j] = *(const f16x8*)(Bs + (wc * 128 + j * 16 + fr) * 32 + fk);
#pragma unroll
        for (int i = 0; i < 2; ++i)
#pragma unroll
            for (int j = 0; j < 8; ++j)
                acc[i][j] = __builtin_amdgcn_mfma_f32_16x16x32_f16(
                    af[i], bf[j], acc[i][j], 0, 0, 0);
        __syncthreads();
    }

    const int cr = (ln >> 4) * 4, cc = ln & 15;
    const int bb = m0 >> 12, l00 = m0 & 4095;

    if (kind < 2) {
        const float* gsrc = kind ? kg : qg;
        _Float16* P = kind ? Kg : Qg;
#pragma unroll
        for (int p = 0; p < 4; ++p) {
            const int h = wc * 4 + p;
            const float g0 = gsrc[h * 32 + cc];
            const float g1 = gsrc[h * 32 + 16 + cc];
#pragma unroll
            for (int i = 0; i < 2; ++i)
#pragma unroll
                for (int r = 0; r < 4; ++r) {
                    const float a0 = acc[i][2 * p][r];
                    const float a1 = acc[i][2 * p + 1][r];
                    float ss = a0 * a0 + a1 * a1;
                    ss += __shfl_xor(ss, 1);
                    ss += __shfl_xor(ss, 2);
                    ss += __shfl_xor(ss, 4);
                    ss += __shfl_xor(ss, 8);
                    // q's D^-1/2 pre-scale cancels (rms-norm scale-invariant)
                    const float sc = 5.656854249492381f / fmaxf(sqrtf(ss), 1e-12f);
                    const int row = wr * 32 + i * 16 + cr + r;
                    Ws[row * 72 + wc * 32 + cc]      = (_Float16)(a0 * sc * g0);
                    Ws[row * 72 + wc * 32 + 16 + cc] = (_Float16)(a1 * sc * g1);
                }
            __syncthreads();
            const int half = tid >> 8;               // 0: head p, 1: head 4+p
            const int t = tid & 255;
            const int hh = half * 4 + p;
            _Float16* dst = P + ((size_t)(bb * 8 + hh) * 4096 + l00) * 32;
#pragma unroll
            for (int cidx = 0; cidx < 2; ++cidx) {
                const int c = t + cidx * 256;        // 0..511 chunks of f16x8
                const int rr = c >> 2, part = (c & 3) * 8;
                f16x8 v8 = *(const f16x8*)(Ws + rr * 72 + half * 32 + part);
                *(f16x8*)(dst + rr * 32 + part) = v8;
            }
            __syncthreads();
        }
    } else {
#pragma unroll
        for (int i = 0; i < 2; ++i)
#pragma unroll
            for (int j = 0; j < 8; ++j) {
                const int col = wc * 128 + j * 16 + cc;
                const int hh = col >> 5, e = col & 31;
                const int l0 = l00 + wr * 32 + i * 16 + cr;
                f16x4 v4 = { (_Float16)acc[i][j][0], (_Float16)acc[i][j][1],
                             (_Float16)acc[i][j][2], (_Float16)acc[i][j][3] };
                *(f16x4*)(Vtg + ((size_t)(bb * 8 + hh) * 32 + e) * 4096 + l0) = v4;
            }
    }
}

// ---------------------------------------------------------------------------
// Per-chunk KV outer product, broadcast-structured:
// thread = (d, e-quad); per pos: 1 b32 bcast + 1 b128 bcast + 4 FMA.
// ---------------------------------------------------------------------------
__global__ __launch_bounds__(256) void k_chunk_kv(
    const _Float16* __restrict__ Kg, const _Float16* __restrict__ Vtg,
    float* __restrict__ kvbuf)
{
    __shared__ float ks[128 * 32];     // [pos][d]
    __shared__ float vs[128 * 36];     // [pos][e] stride 36 (16B-aligned rows)
    const int blk = blockIdx.x;
    const int n  = blk & 31;
    const int bh = blk >> 5;
    const int h  = bh & 7;
    const float sl2 = exp2f(-(float)(h + 1)) * 1.44269504f;
    const int tid = threadIdx.x;
    const _Float16* Kc = Kg + ((size_t)bh * 4096 + n * CHUNK_) * 32;
#pragma unroll
    for (int i = 0; i < 2; ++i) {
        const int flat = i * 256 + tid;
        const int pos = flat >> 2, d0 = (flat & 3) * 8;
        f16x8 k8 = *(const f16x8*)(Kc + flat * 8);
        const float kd = exp2f(-sl2 * (float)(CHUNK_ - pos));
        f32x4 lo = { (float)k8[0] * kd, (float)k8[1] * kd, (float)k8[2] * kd, (float)k8[3] * kd };
        f32x4 hi = { (float)k8[4] * kd, (float)k8[5] * kd, (float)k8[6] * kd, (float)k8[7] * kd };
        *(f32x4*)&ks[pos * 32 + d0]     = lo;
        *(f32x4*)&ks[pos * 32 + d0 + 4] = hi;
        const int e = flat >> 4, seg = flat & 15;
        f16x8 v8 = *(const f16x8*)(Vtg + ((size_t)bh * 32 + e) * 4096 + n * CHUNK_ + seg * 8);
#pragma unroll
        for (int j = 0; j < 8; ++j) vs[(seg * 8 + j) * 36 + e] = (float)v8[j];
    }
    __syncthreads();
    const int d = tid >> 3;            // 0..31
    const int e0 = (tid & 7) * 4;      // 0,4,...,28
    f32x4 acc = {0.f, 0.f, 0.f, 0.f};
    for (int pos = 0; pos < CHUNK_; ++pos) {
        const float kd = ks[pos * 32 + d];
        f32x4 v4 = *(const f32x4*)&vs[pos * 36 + e0];
        acc += kd * v4;
    }
    *(f32x4*)(kvbuf + (size_t)blk * 1024 + d * 32 + e0) = acc;
}

// ---------------------------------------------------------------------------
// Chunk-state scan, batched prefetch.
// ---------------------------------------------------------------------------
__global__ __launch_bounds__(256) void k_scan(float* __restrict__ kvbuf)
{
    const int bh = blockIdx.x;
    const int tid = threadIdx.x;
    const float slope = exp2f(-(float)((bh & 7) + 1));
    const float bd = __expf(-slope * (float)CHUNK_);
    float4 st = {0.f, 0.f, 0.f, 0.f};
    float4* base = (float4*)(kvbuf + (size_t)bh * NC_ * 1024) + tid;
#pragma unroll
    for (int g = 0; g < 4; ++g) {
        float4 tmp[8];
#pragma unroll
        for (int k = 0; k < 8; ++k) tmp[k] = base[(g * 8 + k) * 256];
#pragma unroll
        for (int k = 0; k < 8; ++k) {
            base[(g * 8 + k) * 256] = st;
            st.x = bd * st.x + tmp[k].x;
            st.y = bd * st.y + tmp[k].y;
            st.z = bd * st.z + tmp[k].z;
            st.w = bd * st.w + tmp[k].w;
        }
    }
}

// ---------------------------------------------------------------------------
// MFMA attention per (b,h,chunk): S=Q K^T, decay-mask, O = S̃ V + qd·(Q KV).
// ---------------------------------------------------------------------------
__global__ __launch_bounds__(256) void k_attn(
    const _Float16* __restrict__ Qg, const _Float16* __restrict__ Kg,
    const _Float16* __restrict__ Vtg, const float* __restrict__ kvbuf,
    _Float16* __restrict__ attnp)
{
    __shared__ _Float16 Qs[128 * 32];
    __shared__ _Float16 Ks[128 * 32];
    __shared__ _Float16 Vt[32 * 136];
    __shared__ _Float16 KVt[32 * 40];
    __shared__ _Float16 Ss[128 * 136];
    __shared__ _Float16 Os[128 * 36];
    __shared__ float ejs[CHUNK_];
    const int blk = blockIdx.x;
    const int n  = blk & 31;
    const int bh = blk >> 5;
    const int h  = bh & 7;
    const float sl2 = exp2f(-(float)(h + 1)) * 1.44269504f;
    const int tid = threadIdx.x;
    const int wv = tid >> 6, ln = tid & 63;

    const _Float16* Qc = Qg + ((size_t)bh * 4096 + n * CHUNK_) * 32;
    const _Float16* Kc = Kg + ((size_t)bh * 4096 + n * CHUNK_) * 32;
#pragma unroll
    for (int i = 0; i < 2; ++i) {
        GLOAD_LDS16(Qc + (wv * 128 + i * 64 + ln) * 8, Qs + (wv * 128 + i * 64) * 8);
        GLOAD_LDS16(Kc + (wv * 128 + i * 64 + ln) * 8, Ks + (wv * 128 + i * 64) * 8);
    }
#pragma unroll
    for (int i = 0; i < 2; ++i) {
        int flat = i * 256 + tid;
        int e = flat >> 4, seg = flat & 15;
        f16x8 v8 = *(const f16x8*)(Vtg + ((size_t)bh * 32 + e) * 4096 + n * CHUNK_ + seg * 8);
        *(f16x8*)(Vt + e * 136 + seg * 8) = v8;
    }
    {
        int e = tid & 31, dg = tid >> 5;
        const float* kvp = kvbuf + (size_t)blk * 1024;
        f16x4 kv4 = { (_Float16)kvp[(dg * 4 + 0) * 32 + e],
                      (_Float16)kvp[(dg * 4 + 1) * 32 + e],
                      (_Float16)kvp[(dg * 4 + 2) * 32 + e],
                      (_Float16)kvp[(dg * 4 + 3) * 32 + e] };
        *(f16x4*)(KVt + e * 40 + dg * 4) = kv4;
    }
    if (tid < CHUNK_) ejs[tid] = exp2f(sl2 * (float)tid);
    __syncthreads();

    const int fr = ln & 15, fk = (ln >> 4) * 8;
    const int cr = (ln >> 4) * 4, cc = ln & 15;

    f16x8 aq[2];
#pragma unroll
    for (int i = 0; i < 2; ++i)
        aq[i] = *(const f16x8*)(Qs + (wv * 32 + i * 16 + fr) * 32 + fk);

    f32x4 sacc[2][8] = {};
#pragma unroll
    for (int j = 0; j < 8; ++j) {
        f16x8 bk = *(const f16x8*)(Ks + (j * 16 + fr) * 32 + fk);
#pragma unroll
        for (int i = 0; i < 2; ++i)
            sacc[i][j] = __builtin_amdgcn_mfma_f32_16x16x32_f16(aq[i], bk, sacc[i][j], 0, 0, 0);
    }
    f32x4 iacc[2][2] = {};
#pragma unroll
    for (int ct = 0; ct < 2; ++ct) {
        f16x8 bkv = *(const f16x8*)(KVt + (ct * 16 + fr) * 40 + fk);
#pragma unroll
        for (int i = 0; i < 2; ++i)
            iacc[i][ct] = __builtin_amdgcn_mfma_f32_16x16x32_f16(aq[i], bkv, iacc[i][ct], 0, 0, 0);
    }
    float ejr[8];
#pragma unroll
    for (int j = 0; j < 8; ++j) ejr[j] = ejs[j * 16 + cc];
    const float c1 = exp2f(-sl2);
    float qd_save[2][4];
#pragma unroll
    for (int i = 0; i < 2; ++i) {
        float er = exp2f(-sl2 * (float)(wv * 32 + i * 16 + cr));
#pragma unroll
        for (int r = 0; r < 4; ++r) {
            const int irow = wv * 32 + i * 16 + cr + r;
            qd_save[i][r] = er;
#pragma unroll
            for (int j = 0; j < 8; ++j) {
                const int jcol = j * 16 + cc;
                const float w = (jcol <= irow) ? ejr[j] * er : 0.f;
                Ss[irow * 136 + jcol] = (_Float16)(sacc[i][j][r] * w);
            }
            er *= c1;
        }
    }
    __syncthreads();

    f32x4 oacc[2][2] = {};
#pragma unroll
    for (int k = 0; k < 4; ++k) {
        f16x8 as[2], bv[2];
#pragma unroll
        for (int i = 0; i < 2; ++i)
            as[i] = *(const f16x8*)(Ss + (wv * 32 + i * 16 + fr) * 136 + k * 32 + fk);
#pragma unroll
        for (int ct = 0; ct < 2; ++ct)
            bv[ct] = *(const f16x8*)(Vt + (ct * 16 + fr) * 136 + k * 32 + fk);
#pragma unroll
        for (int i = 0; i < 2; ++i)
#pragma unroll
            for (int ct = 0; ct < 2; ++ct)
                oacc[i][ct] = __builtin_amdgcn_mfma_f32_16x16x32_f16(as[i], bv[ct], oacc[i][ct], 0, 0, 0);
    }
#pragma unroll
    for (int i = 0; i < 2; ++i)
#pragma unroll
        for (int r = 0; r < 4; ++r) {
            const int irow = wv * 32 + i * 16 + cr + r;
            const float qd = qd_save[i][r];
            Os[irow * 36 + cc]      = (_Float16)(oacc[i][0][r] + qd * iacc[i][0][r]);
            Os[irow * 36 + 16 + cc] = (_Float16)(oacc[i][1][r] + qd * iacc[i][1][r]);
        }
    __syncthreads();
    _Float16* abase = attnp + ((size_t)bh * 4096 + n * CHUNK_) * 32;
#pragma unroll
    for (int kk = 0; kk < 2; ++kk) {
        const int c = kk * 256 + tid;
        const int rr = c >> 2;
        const int part = (c & 3) * 8;
        *(f16x8*)(abase + rr * 32 + part) = *(const f16x8*)(Os + rr * 36 + part);
    }
}

// ---------------------------------------------------------------------------
// proj GEMM: out = attn @ proj_w^T + b, A from packed [bh][l][32].
// ---------------------------------------------------------------------------
__global__ __launch_bounds__(256) void k_proj_gemm(
    const _Float16* __restrict__ attnp, const _Float16* __restrict__ Bw,
    const float* __restrict__ bias, float* __restrict__ Cc)
{
    __shared__ _Float16 As[128 * 32];
    __shared__ _Float16 Bs[128 * 32];
    const int tid = threadIdx.x;
    const int wv = tid >> 6, ln = tid & 63;
    const int m0 = blockIdx.y * 128;
    const int n0 = blockIdx.x * 128;
    const int lr = ln >> 2;
    const int lc = (ln & 3) * 8;
    const int wm = (wv >> 1) * 64;
    const int wn = (wv & 1) * 64;
    const int fr = ln & 15;
    const int fk = (ln >> 4) * 8;

    f32x4 acc[4][4] = {};
    const int gmrow = m0 + wv * 16 + lr;
    const _Float16* ga = attnp +
        ((size_t)(gmrow >> 12) * 8 * 4096 + (gmrow & 4095)) * 32 + lc;
    const _Float16* gb = Bw + (size_t)(n0 + wv * 16 + lr) * 256 + lc;

    for (int k0 = 0; k0 < 256; k0 += 32) {
        const size_t hoff = (size_t)(k0 >> 5) * (4096 * 32);
        GLOAD_LDS16(ga + hoff,           As + (wv * 16) * 32);
        GLOAD_LDS16(ga + hoff + 64 * 32, As + (64 + wv * 16) * 32);
        GLOAD_LDS16(gb + k0,             Bs + (wv * 16) * 32);
        GLOAD_LDS16(gb + k0 + 64 * 256,  Bs + (64 + wv * 16) * 32);
        __syncthreads();
        f16x8 af[4], bf[4];
#pragma unroll
        for (int i = 0; i < 4; ++i)
            af[i] = *(const f16x8*)(As + (wm + i * 16 + fr) * 32 + fk);
#pragma unroll
        for (int j = 0; j < 4; ++j)
            bf[j] = *(const f16x8*)(Bs + (wn + j * 16 + fr) * 32 + fk);
#pragma unroll
        for (int i = 0; i < 4; ++i)
#pragma unroll
            for (int j = 0; j < 4; ++j)
                acc[i][j] = __builtin_amdgcn_mfma_f32_16x16x32_f16(
                    af[i], bf[j], acc[i][j], 0, 0, 0);
        __syncthreads();
    }
    const int cr = (ln >> 4) * 4;
    const int cc = ln & 15;
#pragma unroll
    for (int i = 0; i < 4; ++i)
#pragma unroll
        for (int j = 0; j < 4; ++j) {
            const int row = m0 + wm + i * 16 + cr;
            const int col = n0 + wn + j * 16 + cc;
            float* cp = Cc + (size_t)row * 256 + col;
            const float bb = bias[col];
#pragma unroll
            for (int r = 0; r < 4; ++r) cp[(size_t)r * 256] = acc[i][j][r] + bb;
        }
}

// ---------------------------------------------------------------------------
extern "C" void kernel_launch(void* const* d_in, const int* in_sizes, int n_in,
                              void* d_out, int out_size, void* d_ws, size_t ws_size,
                              hipStream_t stream)
{
    const float* x     = (const float*)d_in[0];
    const float* rel   = (const float*)d_in[1];
    const float* qkv_w = (const float*)d_in[2];
    const float* qg    = (const float*)d_in[3];
    const float* kg    = (const float*)d_in[4];
    const float* pw    = (const float*)d_in[5];
    const float* pb    = (const float*)d_in[6];
    float* out = (float*)d_out;
    char* wsb = (char*)d_ws;

    float*    kvb   = (float*)wsb;                            // 8 MB
    _Float16* Qg    = (_Float16*)(wsb + ((size_t)8  << 20));  // 16 MB
    _Float16* Kg    = (_Float16*)(wsb + ((size_t)24 << 20));  // 16 MB
    _Float16* Vtg   = (_Float16*)(wsb + ((size_t)40 << 20));  // 16 MB
    _Float16* attnp = (_Float16*)(wsb + ((size_t)56 << 20));  // 16 MB
    _Float16* qwb   = (_Float16*)(wsb + ((size_t)72 << 20));  // 384 KB
    _Float16* pwb   = (_Float16*)(wsb + ((size_t)73 << 20));  // 128 KB

    k_cast_w<<<256, 256, 0, stream>>>(qkv_w, pw, qwb, pwb);
    k_qkv_fused<<<dim3(3, 256), 512, 0, stream>>>(x, rel, qwb, qg, kg, Qg, Kg, Vtg);
    k_chunk_kv<<<2048, 256, 0, stream>>>(Kg, Vtg, kvb);
    k_scan<<<64, 256, 0, stream>>>(kvb);
    k_attn<<<2048, 256, 0, stream>>>(Qg, Kg, Vtg, kvb, attnp);
    k_proj_gemm<<<dim3(2, 256), 256, 0, stream>>>(attnp, pwb, pb, out);
}

// Round 6
// 188.308 us; speedup vs baseline: 3.0772x; 1.0800x over previous
//
#include <hip/hip_runtime.h>
#include <hip/hip_bf16.h>

#define B_ 8
#define L_ 4096
#define C_ 256
#define H_ 8
#define D_ 32
#define CHUNK_ 128
#define NC_ 32
#define M_ (B_*L_)   // 32768

typedef _Float16 f16x8 __attribute__((ext_vector_type(8)));
typedef _Float16 f16x4 __attribute__((ext_vector_type(4)));
typedef float    f32x4 __attribute__((ext_vector_type(4)));

#define GLOAD_LDS16(g, l) __builtin_amdgcn_global_load_lds( \
    (const __attribute__((address_space(1))) unsigned int*)(g), \
    (__attribute__((address_space(3))) unsigned int*)(l), 16, 0, 0)

// ---------------------------------------------------------------------------
// h = f16(x + rel_pos)
// ---------------------------------------------------------------------------
__global__ __launch_bounds__(256) void k_cast_h(
    const float* __restrict__ x, const float* __restrict__ rel, _Float16* __restrict__ h)
{
    const int i = (blockIdx.x * 256 + threadIdx.x) * 8;
    float4 x0 = *(const float4*)(x + i);
    float4 x1 = *(const float4*)(x + i + 4);
    const int ri = i & (L_ * C_ - 1);
    float4 r0 = *(const float4*)(rel + ri);
    float4 r1 = *(const float4*)(rel + ri + 4);
    f16x8 o = { (_Float16)(x0.x + r0.x), (_Float16)(x0.y + r0.y),
                (_Float16)(x0.z + r0.z), (_Float16)(x0.w + r0.w),
                (_Float16)(x1.x + r1.x), (_Float16)(x1.y + r1.y),
                (_Float16)(x1.z + r1.z), (_Float16)(x1.w + r1.w) };
    *(f16x8*)(h + i) = o;
}

// ---------------------------------------------------------------------------
// Weights -> f16
// ---------------------------------------------------------------------------
__global__ __launch_bounds__(256) void k_cast_w(
    const float* __restrict__ qw, const float* __restrict__ pw,
    _Float16* __restrict__ qwb, _Float16* __restrict__ pwb)
{
    const int i = (blockIdx.x * 256 + threadIdx.x) * 4;
    const float* src; _Float16* dst; int off;
    if (i < 768 * 256) { src = qw; dst = qwb; off = i; }
    else               { src = pw; dst = pwb; off = i - 768 * 256; }
    float4 v = *(const float4*)(src + off);
    f16x4 o = { (_Float16)v.x, (_Float16)v.y, (_Float16)v.z, (_Float16)v.w };
    *(f16x4*)(dst + off) = o;
}

// ---------------------------------------------------------------------------
// qkv GEMM, m97-style: grid (6, 256), 256 thr, 128x128 tile, BK=32,
// A = h (f16) and B both staged via global_load_lds. Epilogue fuses RMS-norm
// (Q/K) -> packed Qg/Kg [bh][l][32]; V -> LDS transpose -> Vtg [bh][e][4096].
// Ws (35 KB) is unioned over As/Bs (dead after the K-loop).
// ---------------------------------------------------------------------------
__global__ __launch_bounds__(256) void k_qkv_gemm(
    const _Float16* __restrict__ A, const _Float16* __restrict__ Bw,
    const float* __restrict__ qg, const float* __restrict__ kg,
    _Float16* __restrict__ Qg, _Float16* __restrict__ Kg, _Float16* __restrict__ Vtg)
{
    __shared__ __align__(16) char smem[34816];      // max(As+Bs=16K, Ws=34816)
    _Float16* As = (_Float16*)smem;                 // [128][32]
    _Float16* Bs = As + 128 * 32;                   // [128][32]
    _Float16* Ws = (_Float16*)smem;                 // [128][136] (post-loop)

    const int tid = threadIdx.x;
    const int wv = tid >> 6, ln = tid & 63;
    const int m0 = blockIdx.y * 128;
    const int n0 = blockIdx.x * 128;
    const int lr = ln >> 2, lc = (ln & 3) * 8;
    const int wm = (wv >> 1) * 64, wn = (wv & 1) * 64;
    const int fr = ln & 15, fk = (ln >> 4) * 8;

    f32x4 acc[4][4] = {};
    const _Float16* ga = A  + (size_t)(m0 + wv * 16 + lr) * 256 + lc;
    const _Float16* gb = Bw + (size_t)(n0 + wv * 16 + lr) * 256 + lc;

    for (int k0 = 0; k0 < 256; k0 += 32) {
        GLOAD_LDS16(ga + k0,            As + (wv * 16) * 32);
        GLOAD_LDS16(ga + k0 + 64 * 256, As + (64 + wv * 16) * 32);
        GLOAD_LDS16(gb + k0,            Bs + (wv * 16) * 32);
        GLOAD_LDS16(gb + k0 + 64 * 256, Bs + (64 + wv * 16) * 32);
        __syncthreads();
        f16x8 af[4], bf[4];
#pragma unroll
        for (int i = 0; i < 4; ++i)
            af[i] = *(const f16x8*)(As + (wm + i * 16 + fr) * 32 + fk);
#pragma unroll
        for (int j = 0; j < 4; ++j)
            bf[j] = *(const f16x8*)(Bs + (wn + j * 16 + fr) * 32 + fk);
#pragma unroll
        for (int i = 0; i < 4; ++i)
#pragma unroll
            for (int j = 0; j < 4; ++j)
                acc[i][j] = __builtin_amdgcn_mfma_f32_16x16x32_f16(
                    af[i], bf[j], acc[i][j], 0, 0, 0);
        __syncthreads();
    }

    const int cr = (ln >> 4) * 4, cc = ln & 15;
    const int kind = n0 >> 8;                 // 0=Q 1=K 2=V
    const int col0 = (n0 & 255) + wn;
    const int bb = m0 >> 12, l00 = m0 & 4095;
    const int hbase = (n0 & 255) >> 5;

    if (kind < 2) {
        // fused RMS-norm (q's D^-1/2 pre-scale cancels; scale-invariant)
        const float* gsrc = kind ? kg : qg;
        float gma[2][2];
#pragma unroll
        for (int jp = 0; jp < 2; ++jp)
#pragma unroll
            for (int jj = 0; jj < 2; ++jj)
                gma[jp][jj] = gsrc[((col0 >> 5) + jp) * 32 + jj * 16 + cc];
#pragma unroll
        for (int i = 0; i < 4; ++i)
#pragma unroll
            for (int r = 0; r < 4; ++r) {
                const int irow = wm + i * 16 + cr + r;
#pragma unroll
                for (int jp = 0; jp < 2; ++jp) {
                    const float a0 = acc[i][jp * 2][r];
                    const float a1 = acc[i][jp * 2 + 1][r];
                    float ss = a0 * a0 + a1 * a1;
                    ss += __shfl_xor(ss, 1);
                    ss += __shfl_xor(ss, 2);
                    ss += __shfl_xor(ss, 4);
                    ss += __shfl_xor(ss, 8);
                    const float sc = 5.656854249492381f / fmaxf(sqrtf(ss), 1e-12f);
                    Ws[irow * 136 + wn + jp * 32 + cc]      = (_Float16)(a0 * sc * gma[jp][0]);
                    Ws[irow * 136 + wn + jp * 32 + 16 + cc] = (_Float16)(a1 * sc * gma[jp][1]);
                }
            }
        __syncthreads();
        _Float16* P = kind ? Kg : Qg;
#pragma unroll
        for (int kk = 0; kk < 8; ++kk) {
            const int c = kk * 256 + tid;             // 0..2047 f16x8 chunks
            const int hh = c >> 9;                    // head within tile
            const int rr = (c >> 2) & 127;            // row
            const int part = (c & 3) * 8;
            f16x8 v8 = *(const f16x8*)(Ws + rr * 136 + hh * 32 + part);
            *(f16x8*)(P + ((size_t)(bb * 8 + hbase + hh) * 4096 + l00 + rr) * 32 + part) = v8;
        }
    } else {
        // V: transpose through LDS -> coalesced 16B stores into [bh][e][4096]
#pragma unroll
        for (int i = 0; i < 4; ++i)
#pragma unroll
            for (int j = 0; j < 4; ++j) {
                const int colL = wn + j * 16 + cc;    // 0..127
                const int row0 = wm + i * 16 + cr;    // 4-aligned
                f16x4 v4 = { (_Float16)acc[i][j][0], (_Float16)acc[i][j][1],
                             (_Float16)acc[i][j][2], (_Float16)acc[i][j][3] };
                *(f16x4*)(Ws + colL * 136 + row0) = v4;
            }
        __syncthreads();
#pragma unroll
        for (int kk = 0; kk < 8; ++kk) {
            const int q = kk * 256 + tid;             // 0..2047
            const int c = q >> 4;                     // col 0..127
            const int seg = q & 15;                   // 8-row segment
            const int col = (n0 & 255) + c;
            const int hh = col >> 5, e = col & 31;
            f16x8 v8 = *(const f16x8*)(Ws + c * 136 + seg * 8);
            *(f16x8*)(Vtg + ((size_t)(bb * 8 + hh) * 32 + e) * 4096 + l00 + seg * 8) = v8;
        }
    }
}

// ---------------------------------------------------------------------------
// Per-chunk KV outer product, broadcast-structured.
// ---------------------------------------------------------------------------
__global__ __launch_bounds__(256) void k_chunk_kv(
    const _Float16* __restrict__ Kg, const _Float16* __restrict__ Vtg,
    float* __restrict__ kvbuf)
{
    __shared__ float ks[128 * 32];     // [pos][d]
    __shared__ float vs[128 * 36];     // [pos][e]
    const int blk = blockIdx.x;
    const int n  = blk & 31;
    const int bh = blk >> 5;
    const int h  = bh & 7;
    const float sl2 = exp2f(-(float)(h + 1)) * 1.44269504f;
    const int tid = threadIdx.x;
    const _Float16* Kc = Kg + ((size_t)bh * 4096 + n * CHUNK_) * 32;
#pragma unroll
    for (int i = 0; i < 2; ++i) {
        const int flat = i * 256 + tid;
        const int pos = flat >> 2, d0 = (flat & 3) * 8;
        f16x8 k8 = *(const f16x8*)(Kc + flat * 8);
        const float kd = exp2f(-sl2 * (float)(CHUNK_ - pos));
        f32x4 lo = { (float)k8[0] * kd, (float)k8[1] * kd, (float)k8[2] * kd, (float)k8[3] * kd };
        f32x4 hi = { (float)k8[4] * kd, (float)k8[5] * kd, (float)k8[6] * kd, (float)k8[7] * kd };
        *(f32x4*)&ks[pos * 32 + d0]     = lo;
        *(f32x4*)&ks[pos * 32 + d0 + 4] = hi;
        const int e = flat >> 4, seg = flat & 15;
        f16x8 v8 = *(const f16x8*)(Vtg + ((size_t)bh * 32 + e) * 4096 + n * CHUNK_ + seg * 8);
#pragma unroll
        for (int j = 0; j < 8; ++j) vs[(seg * 8 + j) * 36 + e] = (float)v8[j];
    }
    __syncthreads();
    const int d = tid >> 3;
    const int e0 = (tid & 7) * 4;
    f32x4 acc = {0.f, 0.f, 0.f, 0.f};
    for (int pos = 0; pos < CHUNK_; ++pos) {
        const float kd = ks[pos * 32 + d];
        f32x4 v4 = *(const f32x4*)&vs[pos * 36 + e0];
        acc += kd * v4;
    }
    *(f32x4*)(kvbuf + (size_t)blk * 1024 + d * 32 + e0) = acc;
}

// ---------------------------------------------------------------------------
// Chunk-state scan, batched prefetch.
// ---------------------------------------------------------------------------
__global__ __launch_bounds__(256) void k_scan(float* __restrict__ kvbuf)
{
    const int bh = blockIdx.x;
    const int tid = threadIdx.x;
    const float slope = exp2f(-(float)((bh & 7) + 1));
    const float bd = __expf(-slope * (float)CHUNK_);
    float4 st = {0.f, 0.f, 0.f, 0.f};
    float4* base = (float4*)(kvbuf + (size_t)bh * NC_ * 1024) + tid;
#pragma unroll
    for (int g = 0; g < 4; ++g) {
        float4 tmp[8];
#pragma unroll
        for (int k = 0; k < 8; ++k) tmp[k] = base[(g * 8 + k) * 256];
#pragma unroll
        for (int k = 0; k < 8; ++k) {
            base[(g * 8 + k) * 256] = st;
            st.x = bd * st.x + tmp[k].x;
            st.y = bd * st.y + tmp[k].y;
            st.z = bd * st.z + tmp[k].z;
            st.w = bd * st.w + tmp[k].w;
        }
    }
}

// ---------------------------------------------------------------------------
// MFMA attention, low-LDS: Q/K/V fragments direct from global; only S̃ (and
// the small KV state) round-trip LDS. Os staging aliases Ss (barrier-guarded).
// ---------------------------------------------------------------------------
__global__ __launch_bounds__(256) void k_attn(
    const _Float16* __restrict__ Qg, const _Float16* __restrict__ Kg,
    const _Float16* __restrict__ Vtg, const float* __restrict__ kvbuf,
    _Float16* __restrict__ attnp)
{
    __shared__ __align__(16) _Float16 Ss[128 * 136];  // also Os[128][40] alias
    __shared__ __align__(16) _Float16 KVt[32 * 40];
    __shared__ float ejs[CHUNK_];
    _Float16* Os = Ss;
    const int blk = blockIdx.x;
    const int n  = blk & 31;
    const int bh = blk >> 5;
    const int h  = bh & 7;
    const float sl2 = exp2f(-(float)(h + 1)) * 1.44269504f;
    const int tid = threadIdx.x;
    const int wv = tid >> 6, ln = tid & 63;
    const int fr = ln & 15, fk = (ln >> 4) * 8;
    const int cr = (ln >> 4) * 4, cc = ln & 15;

    const _Float16* Qc = Qg + ((size_t)bh * 4096 + n * CHUNK_) * 32;
    const _Float16* Kc = Kg + ((size_t)bh * 4096 + n * CHUNK_) * 32;
    const _Float16* Vc = Vtg + (size_t)bh * 32 * 4096 + n * CHUNK_;

    {
        const int e = tid & 31, dg = tid >> 5;
        const float* kvp = kvbuf + (size_t)blk * 1024;
        f16x4 kv4 = { (_Float16)kvp[(dg * 4 + 0) * 32 + e],
                      (_Float16)kvp[(dg * 4 + 1) * 32 + e],
                      (_Float16)kvp[(dg * 4 + 2) * 32 + e],
                      (_Float16)kvp[(dg * 4 + 3) * 32 + e] };
        *(f16x4*)(KVt + e * 40 + dg * 4) = kv4;
    }
    if (tid < CHUNK_) ejs[tid] = exp2f(sl2 * (float)tid);
    __syncthreads();

    f16x8 aq[2];
#pragma unroll
    for (int i = 0; i < 2; ++i)
        aq[i] = *(const f16x8*)(Qc + (wv * 32 + i * 16 + fr) * 32 + fk);

    f32x4 sacc[2][8] = {};
#pragma unroll
    for (int j = 0; j < 8; ++j) {
        f16x8 bk = *(const f16x8*)(Kc + (j * 16 + fr) * 32 + fk);
#pragma unroll
        for (int i = 0; i < 2; ++i)
            sacc[i][j] = __builtin_amdgcn_mfma_f32_16x16x32_f16(aq[i], bk, sacc[i][j], 0, 0, 0);
    }
    f32x4 iacc[2][2] = {};
#pragma unroll
    for (int ct = 0; ct < 2; ++ct) {
        f16x8 bkv = *(const f16x8*)(KVt + (ct * 16 + fr) * 40 + fk);
#pragma unroll
        for (int i = 0; i < 2; ++i)
            iacc[i][ct] = __builtin_amdgcn_mfma_f32_16x16x32_f16(aq[i], bkv, iacc[i][ct], 0, 0, 0);
    }
    // decay mask: w = ejs[jcol] * exp2(-sl2*irow), factorized, <= 1
    float ejr[8];
#pragma unroll
    for (int j = 0; j < 8; ++j) ejr[j] = ejs[j * 16 + cc];
    const float c1 = exp2f(-sl2);
    float qd_save[2][4];
#pragma unroll
    for (int i = 0; i < 2; ++i) {
        float er = exp2f(-sl2 * (float)(wv * 32 + i * 16 + cr));
#pragma unroll
        for (int r = 0; r < 4; ++r) {
            const int irow = wv * 32 + i * 16 + cr + r;
            qd_save[i][r] = er;
#pragma unroll
            for (int j = 0; j < 8; ++j) {
                const int jcol = j * 16 + cc;
                const float w = (jcol <= irow) ? ejr[j] * er : 0.f;
                Ss[irow * 136 + jcol] = (_Float16)(sacc[i][j][r] * w);
            }
            er *= c1;
        }
    }
    __syncthreads();

    f32x4 oacc[2][2] = {};
#pragma unroll
    for (int k = 0; k < 4; ++k) {
        f16x8 as[2], bv[2];
#pragma unroll
        for (int i = 0; i < 2; ++i)
            as[i] = *(const f16x8*)(Ss + (wv * 32 + i * 16 + fr) * 136 + k * 32 + fk);
#pragma unroll
        for (int ct = 0; ct < 2; ++ct)
            bv[ct] = *(const f16x8*)(Vc + (size_t)(ct * 16 + fr) * 4096 + k * 32 + fk);
#pragma unroll
        for (int i = 0; i < 2; ++i)
#pragma unroll
            for (int ct = 0; ct < 2; ++ct)
                oacc[i][ct] = __builtin_amdgcn_mfma_f32_16x16x32_f16(as[i], bv[ct], oacc[i][ct], 0, 0, 0);
    }
    __syncthreads();   // all Ss reads complete before Os (alias) is written
#pragma unroll
    for (int i = 0; i < 2; ++i)
#pragma unroll
        for (int r = 0; r < 4; ++r) {
            const int irow = wv * 32 + i * 16 + cr + r;
            const float qd = qd_save[i][r];
            Os[irow * 40 + cc]      = (_Float16)(oacc[i][0][r] + qd * iacc[i][0][r]);
            Os[irow * 40 + 16 + cc] = (_Float16)(oacc[i][1][r] + qd * iacc[i][1][r]);
        }
    __syncthreads();
    _Float16* abase = attnp + ((size_t)bh * 4096 + n * CHUNK_) * 32;
#pragma unroll
    for (int kk = 0; kk < 2; ++kk) {
        const int c = kk * 256 + tid;
        const int rr = c >> 2;
        const int part = (c & 3) * 8;
        *(f16x8*)(abase + rr * 32 + part) = *(const f16x8*)(Os + rr * 40 + part);
    }
}

// ---------------------------------------------------------------------------
// proj GEMM: out = attn @ proj_w^T + b, A from packed [bh][l][32].
// ---------------------------------------------------------------------------
__global__ __launch_bounds__(256) void k_proj_gemm(
    const _Float16* __restrict__ attnp, const _Float16* __restrict__ Bw,
    const float* __restrict__ bias, float* __restrict__ Cc)
{
    __shared__ _Float16 As[128 * 32];
    __shared__ _Float16 Bs[128 * 32];
    const int tid = threadIdx.x;
    const int wv = tid >> 6, ln = tid & 63;
    const int m0 = blockIdx.y * 128;
    const int n0 = blockIdx.x * 128;
    const int lr = ln >> 2;
    const int lc = (ln & 3) * 8;
    const int wm = (wv >> 1) * 64;
    const int wn = (wv & 1) * 64;
    const int fr = ln & 15;
    const int fk = (ln >> 4) * 8;

    f32x4 acc[4][4] = {};
    const int gmrow = m0 + wv * 16 + lr;
    const _Float16* ga = attnp +
        ((size_t)(gmrow >> 12) * 8 * 4096 + (gmrow & 4095)) * 32 + lc;
    const _Float16* gb = Bw + (size_t)(n0 + wv * 16 + lr) * 256 + lc;

    for (int k0 = 0; k0 < 256; k0 += 32) {
        const size_t hoff = (size_t)(k0 >> 5) * (4096 * 32);
        GLOAD_LDS16(ga + hoff,           As + (wv * 16) * 32);
        GLOAD_LDS16(ga + hoff + 64 * 32, As + (64 + wv * 16) * 32);
        GLOAD_LDS16(gb + k0,             Bs + (wv * 16) * 32);
        GLOAD_LDS16(gb + k0 + 64 * 256,  Bs + (64 + wv * 16) * 32);
        __syncthreads();
        f16x8 af[4], bf[4];
#pragma unroll
        for (int i = 0; i < 4; ++i)
            af[i] = *(const f16x8*)(As + (wm + i * 16 + fr) * 32 + fk);
#pragma unroll
        for (int j = 0; j < 4; ++j)
            bf[j] = *(const f16x8*)(Bs + (wn + j * 16 + fr) * 32 + fk);
#pragma unroll
        for (int i = 0; i < 4; ++i)
#pragma unroll
            for (int j = 0; j < 4; ++j)
                acc[i][j] = __builtin_amdgcn_mfma_f32_16x16x32_f16(
                    af[i], bf[j], acc[i][j], 0, 0, 0);
        __syncthreads();
    }
    const int cr = (ln >> 4) * 4;
    const int cc = ln & 15;
#pragma unroll
    for (int i = 0; i < 4; ++i)
#pragma unroll
        for (int j = 0; j < 4; ++j) {
            const int row = m0 + wm + i * 16 + cr;
            const int col = n0 + wn + j * 16 + cc;
            float* cp = Cc + (size_t)row * 256 + col;
            const float bb = bias[col];
#pragma unroll
            for (int r = 0; r < 4; ++r) cp[(size_t)r * 256] = acc[i][j][r] + bb;
        }
}

// ---------------------------------------------------------------------------
extern "C" void kernel_launch(void* const* d_in, const int* in_sizes, int n_in,
                              void* d_out, int out_size, void* d_ws, size_t ws_size,
                              hipStream_t stream)
{
    const float* x     = (const float*)d_in[0];
    const float* rel   = (const float*)d_in[1];
    const float* qkv_w = (const float*)d_in[2];
    const float* qg    = (const float*)d_in[3];
    const float* kg    = (const float*)d_in[4];
    const float* pw    = (const float*)d_in[5];
    const float* pb    = (const float*)d_in[6];
    float* out = (float*)d_out;
    char* wsb = (char*)d_ws;

    float*    kvb   = (float*)wsb;                            // 8 MB
    _Float16* Qg    = (_Float16*)(wsb + ((size_t)8  << 20));  // 16 MB
    _Float16* Kg    = (_Float16*)(wsb + ((size_t)24 << 20));  // 16 MB
    _Float16* Vtg   = (_Float16*)(wsb + ((size_t)40 << 20));  // 16 MB
    _Float16* attnp = (_Float16*)(wsb + ((size_t)56 << 20));  // 16 MB
    _Float16* hb    = (_Float16*)(wsb + ((size_t)72 << 20));  // 16 MB
    _Float16* qwb   = (_Float16*)(wsb + ((size_t)88 << 20));  // 384 KB
    _Float16* pwb   = (_Float16*)(wsb + ((size_t)89 << 20));  // 128 KB

    k_cast_w<<<256, 256, 0, stream>>>(qkv_w, pw, qwb, pwb);
    k_cast_h<<<4096, 256, 0, stream>>>(x, rel, hb);
    k_qkv_gemm<<<dim3(6, 256), 256, 0, stream>>>(hb, qwb, qg, kg, Qg, Kg, Vtg);
    k_chunk_kv<<<2048, 256, 0, stream>>>(Kg, Vtg, kvb);
    k_scan<<<64, 256, 0, stream>>>(kvb);
    k_attn<<<2048, 256, 0, stream>>>(Qg, Kg, Vtg, kvb, attnp);
    k_proj_gemm<<<dim3(2, 256), 256, 0, stream>>>(attnp, pwb, pb, out);
}

// Round 7
// 168.238 us; speedup vs baseline: 3.4443x; 1.1193x over previous
//
#include <hip/hip_runtime.h>
#include <hip/hip_bf16.h>

#define B_ 8
#define L_ 4096
#define C_ 256
#define H_ 8
#define D_ 32
#define CHUNK_ 128
#define NC_ 32
#define M_ (B_*L_)   // 32768

typedef _Float16 f16x8 __attribute__((ext_vector_type(8)));
typedef _Float16 f16x4 __attribute__((ext_vector_type(4)));
typedef float    f32x4 __attribute__((ext_vector_type(4)));

#define GLOAD_LDS16(g, l) __builtin_amdgcn_global_load_lds( \
    (const __attribute__((address_space(1))) unsigned int*)(g), \
    (__attribute__((address_space(3))) unsigned int*)(l), 16, 0, 0)

// ---------------------------------------------------------------------------
// Prep: h = f16(x + rel_pos)  and  weights -> f16   (one launch)
// ---------------------------------------------------------------------------
__global__ __launch_bounds__(256) void k_prep(
    const float* __restrict__ x, const float* __restrict__ rel,
    const float* __restrict__ qw, const float* __restrict__ pw,
    _Float16* __restrict__ h, _Float16* __restrict__ qwb, _Float16* __restrict__ pwb)
{
    const int bx = blockIdx.x;
    if (bx < 4096) {
        const int i = (bx * 256 + threadIdx.x) * 8;
        float4 x0 = *(const float4*)(x + i);
        float4 x1 = *(const float4*)(x + i + 4);
        const int ri = i & (L_ * C_ - 1);
        float4 r0 = *(const float4*)(rel + ri);
        float4 r1 = *(const float4*)(rel + ri + 4);
        f16x8 o = { (_Float16)(x0.x + r0.x), (_Float16)(x0.y + r0.y),
                    (_Float16)(x0.z + r0.z), (_Float16)(x0.w + r0.w),
                    (_Float16)(x1.x + r1.x), (_Float16)(x1.y + r1.y),
                    (_Float16)(x1.z + r1.z), (_Float16)(x1.w + r1.w) };
        *(f16x8*)(h + i) = o;
    } else {
        const int i = ((bx - 4096) * 256 + threadIdx.x) * 4;
        const float* src; _Float16* dst; int off;
        if (i < 768 * 256) { src = qw; dst = qwb; off = i; }
        else               { src = pw; dst = pwb; off = i - 768 * 256; }
        float4 v = *(const float4*)(src + off);
        f16x4 o = { (_Float16)v.x, (_Float16)v.y, (_Float16)v.z, (_Float16)v.w };
        *(f16x4*)(dst + off) = o;
    }
}

// ---------------------------------------------------------------------------
// qkv GEMM, m97-style, XCD-swizzled 1D grid (1536 blocks):
// xcd = blk&7 owns 32 contiguous by-tiles x all 6 bx -> A-tile stays in one
// XCD's L2. Epilogue fuses RMS-norm (Q/K) -> packed Qg/Kg [bh][l][32];
// V -> LDS transpose (stride 132) -> Vtg [bh][e][4096].
// ---------------------------------------------------------------------------
__global__ __launch_bounds__(256) void k_qkv_gemm(
    const _Float16* __restrict__ A, const _Float16* __restrict__ Bw,
    const float* __restrict__ qg, const float* __restrict__ kg,
    _Float16* __restrict__ Qg, _Float16* __restrict__ Kg, _Float16* __restrict__ Vtg)
{
    __shared__ __align__(16) char smem[34816];      // max(As+Bs=16K, Ws)
    _Float16* As = (_Float16*)smem;                 // [128][32]
    _Float16* Bs = As + 128 * 32;                   // [128][32]
    _Float16* Ws = (_Float16*)smem;                 // epilogue staging

    const int blk = blockIdx.x;
    const int xcd = blk & 7;
    const int t   = blk >> 3;                       // 0..191
    const int by  = xcd * 32 + (t & 31);
    const int bx  = t >> 5;                         // 0..5
    const int m0 = by * 128;
    const int n0 = bx * 128;

    const int tid = threadIdx.x;
    const int wv = tid >> 6, ln = tid & 63;
    const int lr = ln >> 2, lc = (ln & 3) * 8;
    const int wm = (wv >> 1) * 64, wn = (wv & 1) * 64;
    const int fr = ln & 15, fk = (ln >> 4) * 8;

    f32x4 acc[4][4] = {};
    const _Float16* ga = A  + (size_t)(m0 + wv * 16 + lr) * 256 + lc;
    const _Float16* gb = Bw + (size_t)(n0 + wv * 16 + lr) * 256 + lc;

    for (int k0 = 0; k0 < 256; k0 += 32) {
        GLOAD_LDS16(ga + k0,            As + (wv * 16) * 32);
        GLOAD_LDS16(ga + k0 + 64 * 256, As + (64 + wv * 16) * 32);
        GLOAD_LDS16(gb + k0,            Bs + (wv * 16) * 32);
        GLOAD_LDS16(gb + k0 + 64 * 256, Bs + (64 + wv * 16) * 32);
        __syncthreads();
        f16x8 af[4], bf[4];
#pragma unroll
        for (int i = 0; i < 4; ++i)
            af[i] = *(const f16x8*)(As + (wm + i * 16 + fr) * 32 + fk);
#pragma unroll
        for (int j = 0; j < 4; ++j)
            bf[j] = *(const f16x8*)(Bs + (wn + j * 16 + fr) * 32 + fk);
#pragma unroll
        for (int i = 0; i < 4; ++i)
#pragma unroll
            for (int j = 0; j < 4; ++j)
                acc[i][j] = __builtin_amdgcn_mfma_f32_16x16x32_f16(
                    af[i], bf[j], acc[i][j], 0, 0, 0);
        __syncthreads();
    }

    const int cr = (ln >> 4) * 4, cc = ln & 15;
    const int kind = n0 >> 8;                 // 0=Q 1=K 2=V
    const int col0 = (n0 & 255) + wn;
    const int bb = m0 >> 12, l00 = m0 & 4095;
    const int hbase = (n0 & 255) >> 5;

    if (kind < 2) {
        // fused RMS-norm (q's D^-1/2 pre-scale cancels; scale-invariant)
        const float* gsrc = kind ? kg : qg;
        float gma[2][2];
#pragma unroll
        for (int jp = 0; jp < 2; ++jp)
#pragma unroll
            for (int jj = 0; jj < 2; ++jj)
                gma[jp][jj] = gsrc[((col0 >> 5) + jp) * 32 + jj * 16 + cc];
#pragma unroll
        for (int i = 0; i < 4; ++i)
#pragma unroll
            for (int r = 0; r < 4; ++r) {
                const int irow = wm + i * 16 + cr + r;
#pragma unroll
                for (int jp = 0; jp < 2; ++jp) {
                    const float a0 = acc[i][jp * 2][r];
                    const float a1 = acc[i][jp * 2 + 1][r];
                    float ss = a0 * a0 + a1 * a1;
                    ss += __shfl_xor(ss, 1);
                    ss += __shfl_xor(ss, 2);
                    ss += __shfl_xor(ss, 4);
                    ss += __shfl_xor(ss, 8);
                    const float sc = 5.656854249492381f / fmaxf(sqrtf(ss), 1e-12f);
                    Ws[irow * 136 + wn + jp * 32 + cc]      = (_Float16)(a0 * sc * gma[jp][0]);
                    Ws[irow * 136 + wn + jp * 32 + 16 + cc] = (_Float16)(a1 * sc * gma[jp][1]);
                }
            }
        __syncthreads();
        _Float16* P = kind ? Kg : Qg;
#pragma unroll
        for (int kk = 0; kk < 8; ++kk) {
            const int c = kk * 256 + tid;             // 0..2047 f16x8 chunks
            const int hh = c >> 9;
            const int rr = (c >> 2) & 127;
            const int part = (c & 3) * 8;
            f16x8 v8 = *(const f16x8*)(Ws + rr * 136 + hh * 32 + part);
            *(f16x8*)(P + ((size_t)(bb * 8 + hbase + hh) * 4096 + l00 + rr) * 32 + part) = v8;
        }
    } else {
        // V: transpose through LDS (stride 132: 2-way banks) -> [bh][e][4096]
#pragma unroll
        for (int i = 0; i < 4; ++i)
#pragma unroll
            for (int j = 0; j < 4; ++j) {
                const int colL = wn + j * 16 + cc;    // 0..127
                const int row0 = wm + i * 16 + cr;    // 4-aligned
                f16x4 v4 = { (_Float16)acc[i][j][0], (_Float16)acc[i][j][1],
                             (_Float16)acc[i][j][2], (_Float16)acc[i][j][3] };
                *(f16x4*)(Ws + colL * 132 + row0) = v4;
            }
        __syncthreads();
#pragma unroll
        for (int kk = 0; kk < 8; ++kk) {
            const int q = kk * 256 + tid;             // 0..2047
            const int c = q >> 4;                     // col 0..127
            const int seg = q & 15;                   // 8-row segment
            const int col = (n0 & 255) + c;
            const int hh = col >> 5, e = col & 31;
            f16x8 v8 = *(const f16x8*)(Ws + c * 132 + seg * 8);
            *(f16x8*)(Vtg + ((size_t)(bb * 8 + hh) * 32 + e) * 4096 + l00 + seg * 8) = v8;
        }
    }
}

// ---------------------------------------------------------------------------
// Per-chunk KV outer product via MFMA: one wave per chunk.
// KV^T[e][d] = sum_pos V[pos][e] * K[pos][d] * exp(-s*(128-pos)).
// A = V^T (Vtg rows), B = K^T (in-LDS scalar transpose), decay folded into
// the B fragment in-register. Output layout [e][d] (transposed vs before).
// ---------------------------------------------------------------------------
__global__ __launch_bounds__(64) void k_chunk_kv(
    const _Float16* __restrict__ Kg, const _Float16* __restrict__ Vtg,
    float* __restrict__ kvbuf)
{
    __shared__ _Float16 Vp[32 * 136];   // [e][pos]
    __shared__ _Float16 Kp[32 * 136];   // [d][pos]
    const int blk = blockIdx.x;
    const int n  = blk & 31;
    const int bh = blk >> 5;
    const int h  = bh & 7;
    const float sl2 = exp2f(-(float)(h + 1)) * 1.44269504f;
    const int ln = threadIdx.x;
    const _Float16* Kc = Kg  + ((size_t)bh * 4096 + n * CHUNK_) * 32;
    const _Float16* Vc = Vtg + (size_t)bh * 32 * 4096 + n * CHUNK_;
#pragma unroll
    for (int i = 0; i < 8; ++i) {
        const int flat = i * 64 + ln;          // 0..511
        const int e = flat >> 4, seg = flat & 15;
        f16x8 v8 = *(const f16x8*)(Vc + (size_t)e * 4096 + seg * 8);
        *(f16x8*)(Vp + e * 136 + seg * 8) = v8;
        const int pos = flat >> 2, d0 = (flat & 3) * 8;
        f16x8 k8 = *(const f16x8*)(Kc + flat * 8);
#pragma unroll
        for (int j = 0; j < 8; ++j) Kp[(d0 + j) * 136 + pos] = k8[j];
    }
    __syncthreads();
    const int fr = ln & 15, fk = (ln >> 4) * 8;
    const float r = exp2f(sl2);
    float rj[8];
    rj[0] = 1.f;
#pragma unroll
    for (int j = 1; j < 8; ++j) rj[j] = rj[j - 1] * r;
    f32x4 acc[2][2] = {};
    for (int k0 = 0; k0 < 128; k0 += 32) {
        const float e0 = exp2f(-sl2 * (float)(CHUNK_ - (k0 + fk)));
        f16x8 av[2], bd[2];
#pragma unroll
        for (int i = 0; i < 2; ++i)
            av[i] = *(const f16x8*)(Vp + (i * 16 + fr) * 136 + k0 + fk);
#pragma unroll
        for (int jt = 0; jt < 2; ++jt) {
            f16x8 kraw = *(const f16x8*)(Kp + (jt * 16 + fr) * 136 + k0 + fk);
            f16x8 kb;
#pragma unroll
            for (int j = 0; j < 8; ++j)
                kb[j] = (_Float16)((float)kraw[j] * (e0 * rj[j]));
            bd[jt] = kb;
        }
#pragma unroll
        for (int i = 0; i < 2; ++i)
#pragma unroll
            for (int jt = 0; jt < 2; ++jt)
                acc[i][jt] = __builtin_amdgcn_mfma_f32_16x16x32_f16(
                    av[i], bd[jt], acc[i][jt], 0, 0, 0);
    }
    const int cr = (ln >> 4) * 4, cc = ln & 15;
    float* outp = kvbuf + (size_t)blk * 1024;
#pragma unroll
    for (int i = 0; i < 2; ++i)
#pragma unroll
        for (int jt = 0; jt < 2; ++jt)
#pragma unroll
            for (int rr = 0; rr < 4; ++rr)
                outp[(i * 16 + cr + rr) * 32 + jt * 16 + cc] = acc[i][jt][rr];
}

// ---------------------------------------------------------------------------
// Chunk-state scan, batched prefetch (layout-agnostic: flat 1024 per chunk).
// ---------------------------------------------------------------------------
__global__ __launch_bounds__(256) void k_scan(float* __restrict__ kvbuf)
{
    const int bh = blockIdx.x;
    const int tid = threadIdx.x;
    const float slope = exp2f(-(float)((bh & 7) + 1));
    const float bd = __expf(-slope * (float)CHUNK_);
    float4 st = {0.f, 0.f, 0.f, 0.f};
    float4* base = (float4*)(kvbuf + (size_t)bh * NC_ * 1024) + tid;
#pragma unroll
    for (int g = 0; g < 4; ++g) {
        float4 tmp[8];
#pragma unroll
        for (int k = 0; k < 8; ++k) tmp[k] = base[(g * 8 + k) * 256];
#pragma unroll
        for (int k = 0; k < 8; ++k) {
            base[(g * 8 + k) * 256] = st;
            st.x = bd * st.x + tmp[k].x;
            st.y = bd * st.y + tmp[k].y;
            st.z = bd * st.z + tmp[k].z;
            st.w = bd * st.w + tmp[k].w;
        }
    }
}

// ---------------------------------------------------------------------------
// MFMA attention, low-LDS: Q/K/V fragments direct from global; only S̃ (and
// the small KV state) round-trip LDS. Os staging aliases Ss (barrier-guarded).
// kvbuf is [e][d] (KV^T) -> straight vector copy into KVt.
// ---------------------------------------------------------------------------
__global__ __launch_bounds__(256) void k_attn(
    const _Float16* __restrict__ Qg, const _Float16* __restrict__ Kg,
    const _Float16* __restrict__ Vtg, const float* __restrict__ kvbuf,
    _Float16* __restrict__ attnp)
{
    __shared__ __align__(16) _Float16 Ss[128 * 136];  // also Os[128][40] alias
    __shared__ __align__(16) _Float16 KVt[32 * 40];
    __shared__ float ejs[CHUNK_];
    _Float16* Os = Ss;
    const int blk = blockIdx.x;
    const int n  = blk & 31;
    const int bh = blk >> 5;
    const int h  = bh & 7;
    const float sl2 = exp2f(-(float)(h + 1)) * 1.44269504f;
    const int tid = threadIdx.x;
    const int wv = tid >> 6, ln = tid & 63;
    const int fr = ln & 15, fk = (ln >> 4) * 8;
    const int cr = (ln >> 4) * 4, cc = ln & 15;

    const _Float16* Qc = Qg + ((size_t)bh * 4096 + n * CHUNK_) * 32;
    const _Float16* Kc = Kg + ((size_t)bh * 4096 + n * CHUNK_) * 32;
    const _Float16* Vc = Vtg + (size_t)bh * 32 * 4096 + n * CHUNK_;

    {
        // kvbuf [e][d]: tid*4 covers 1024; e = tid>>3, d0 = (tid&7)*4
        const float* kvp = kvbuf + (size_t)blk * 1024;
        f32x4 kv4f = *(const f32x4*)(kvp + tid * 4);
        f16x4 kv4 = { (_Float16)kv4f[0], (_Float16)kv4f[1],
                      (_Float16)kv4f[2], (_Float16)kv4f[3] };
        *(f16x4*)(KVt + (tid >> 3) * 40 + (tid & 7) * 4) = kv4;
    }
    if (tid < CHUNK_) ejs[tid] = exp2f(sl2 * (float)tid);
    __syncthreads();

    f16x8 aq[2];
#pragma unroll
    for (int i = 0; i < 2; ++i)
        aq[i] = *(const f16x8*)(Qc + (wv * 32 + i * 16 + fr) * 32 + fk);

    f32x4 sacc[2][8] = {};
#pragma unroll
    for (int j = 0; j < 8; ++j) {
        f16x8 bk = *(const f16x8*)(Kc + (j * 16 + fr) * 32 + fk);
#pragma unroll
        for (int i = 0; i < 2; ++i)
            sacc[i][j] = __builtin_amdgcn_mfma_f32_16x16x32_f16(aq[i], bk, sacc[i][j], 0, 0, 0);
    }
    f32x4 iacc[2][2] = {};
#pragma unroll
    for (int ct = 0; ct < 2; ++ct) {
        f16x8 bkv = *(const f16x8*)(KVt + (ct * 16 + fr) * 40 + fk);
#pragma unroll
        for (int i = 0; i < 2; ++i)
            iacc[i][ct] = __builtin_amdgcn_mfma_f32_16x16x32_f16(aq[i], bkv, iacc[i][ct], 0, 0, 0);
    }
    // decay mask: w = ejs[jcol] * exp2(-sl2*irow), factorized, <= 1
    float ejr[8];
#pragma unroll
    for (int j = 0; j < 8; ++j) ejr[j] = ejs[j * 16 + cc];
    const float c1 = exp2f(-sl2);
    float qd_save[2][4];
#pragma unroll
    for (int i = 0; i < 2; ++i) {
        float er = exp2f(-sl2 * (float)(wv * 32 + i * 16 + cr));
#pragma unroll
        for (int r = 0; r < 4; ++r) {
            const int irow = wv * 32 + i * 16 + cr + r;
            qd_save[i][r] = er;
#pragma unroll
            for (int j = 0; j < 8; ++j) {
                const int jcol = j * 16 + cc;
                const float w = (jcol <= irow) ? ejr[j] * er : 0.f;
                Ss[irow * 136 + jcol] = (_Float16)(sacc[i][j][r] * w);
            }
            er *= c1;
        }
    }
    __syncthreads();

    f32x4 oacc[2][2] = {};
#pragma unroll
    for (int k = 0; k < 4; ++k) {
        f16x8 as[2], bv[2];
#pragma unroll
        for (int i = 0; i < 2; ++i)
            as[i] = *(const f16x8*)(Ss + (wv * 32 + i * 16 + fr) * 136 + k * 32 + fk);
#pragma unroll
        for (int ct = 0; ct < 2; ++ct)
            bv[ct] = *(const f16x8*)(Vc + (size_t)(ct * 16 + fr) * 4096 + k * 32 + fk);
#pragma unroll
        for (int i = 0; i < 2; ++i)
#pragma unroll
            for (int ct = 0; ct < 2; ++ct)
                oacc[i][ct] = __builtin_amdgcn_mfma_f32_16x16x32_f16(as[i], bv[ct], oacc[i][ct], 0, 0, 0);
    }
    __syncthreads();   // all Ss reads complete before Os (alias) is written
#pragma unroll
    for (int i = 0; i < 2; ++i)
#pragma unroll
        for (int r = 0; r < 4; ++r) {
            const int irow = wv * 32 + i * 16 + cr + r;
            const float qd = qd_save[i][r];
            Os[irow * 40 + cc]      = (_Float16)(oacc[i][0][r] + qd * iacc[i][0][r]);
            Os[irow * 40 + 16 + cc] = (_Float16)(oacc[i][1][r] + qd * iacc[i][1][r]);
        }
    __syncthreads();
    _Float16* abase = attnp + ((size_t)bh * 4096 + n * CHUNK_) * 32;
#pragma unroll
    for (int kk = 0; kk < 2; ++kk) {
        const int c = kk * 256 + tid;
        const int rr = c >> 2;
        const int part = (c & 3) * 8;
        *(f16x8*)(abase + rr * 32 + part) = *(const f16x8*)(Os + rr * 40 + part);
    }
}

// ---------------------------------------------------------------------------
// proj GEMM: out = attn @ proj_w^T + b, A from packed [bh][l][32].
// XCD-swizzled 1D grid (512 blocks).
// ---------------------------------------------------------------------------
__global__ __launch_bounds__(256) void k_proj_gemm(
    const _Float16* __restrict__ attnp, const _Float16* __restrict__ Bw,
    const float* __restrict__ bias, float* __restrict__ Cc)
{
    __shared__ _Float16 As[128 * 32];
    __shared__ _Float16 Bs[128 * 32];
    const int blk = blockIdx.x;
    const int xcd = blk & 7;
    const int t   = blk >> 3;                       // 0..63
    const int m0 = (xcd * 32 + (t & 31)) * 128;
    const int n0 = (t >> 5) * 128;

    const int tid = threadIdx.x;
    const int wv = tid >> 6, ln = tid & 63;
    const int lr = ln >> 2;
    const int lc = (ln & 3) * 8;
    const int wm = (wv >> 1) * 64;
    const int wn = (wv & 1) * 64;
    const int fr = ln & 15;
    const int fk = (ln >> 4) * 8;

    f32x4 acc[4][4] = {};
    const int gmrow = m0 + wv * 16 + lr;
    const _Float16* ga = attnp +
        ((size_t)(gmrow >> 12) * 8 * 4096 + (gmrow & 4095)) * 32 + lc;
    const _Float16* gb = Bw + (size_t)(n0 + wv * 16 + lr) * 256 + lc;

    for (int k0 = 0; k0 < 256; k0 += 32) {
        const size_t hoff = (size_t)(k0 >> 5) * (4096 * 32);
        GLOAD_LDS16(ga + hoff,           As + (wv * 16) * 32);
        GLOAD_LDS16(ga + hoff + 64 * 32, As + (64 + wv * 16) * 32);
        GLOAD_LDS16(gb + k0,             Bs + (wv * 16) * 32);
        GLOAD_LDS16(gb + k0 + 64 * 256,  Bs + (64 + wv * 16) * 32);
        __syncthreads();
        f16x8 af[4], bf[4];
#pragma unroll
        for (int i = 0; i < 4; ++i)
            af[i] = *(const f16x8*)(As + (wm + i * 16 + fr) * 32 + fk);
#pragma unroll
        for (int j = 0; j < 4; ++j)
            bf[j] = *(const f16x8*)(Bs + (wn + j * 16 + fr) * 32 + fk);
#pragma unroll
        for (int i = 0; i < 4; ++i)
#pragma unroll
            for (int j = 0; j < 4; ++j)
                acc[i][j] = __builtin_amdgcn_mfma_f32_16x16x32_f16(
                    af[i], bf[j], acc[i][j], 0, 0, 0);
        __syncthreads();
    }
    const int cr = (ln >> 4) * 4;
    const int cc = ln & 15;
#pragma unroll
    for (int i = 0; i < 4; ++i)
#pragma unroll
        for (int j = 0; j < 4; ++j) {
            const int row = m0 + wm + i * 16 + cr;
            const int col = n0 + wn + j * 16 + cc;
            float* cp = Cc + (size_t)row * 256 + col;
            const float bb = bias[col];
#pragma unroll
            for (int r = 0; r < 4; ++r) cp[(size_t)r * 256] = acc[i][j][r] + bb;
        }
}

// ---------------------------------------------------------------------------
extern "C" void kernel_launch(void* const* d_in, const int* in_sizes, int n_in,
                              void* d_out, int out_size, void* d_ws, size_t ws_size,
                              hipStream_t stream)
{
    const float* x     = (const float*)d_in[0];
    const float* rel   = (const float*)d_in[1];
    const float* qkv_w = (const float*)d_in[2];
    const float* qg    = (const float*)d_in[3];
    const float* kg    = (const float*)d_in[4];
    const float* pw    = (const float*)d_in[5];
    const float* pb    = (const float*)d_in[6];
    float* out = (float*)d_out;
    char* wsb = (char*)d_ws;

    float*    kvb   = (float*)wsb;                            // 8 MB
    _Float16* Qg    = (_Float16*)(wsb + ((size_t)8  << 20));  // 16 MB
    _Float16* Kg    = (_Float16*)(wsb + ((size_t)24 << 20));  // 16 MB
    _Float16* Vtg   = (_Float16*)(wsb + ((size_t)40 << 20));  // 16 MB
    _Float16* attnp = (_Float16*)(wsb + ((size_t)56 << 20));  // 16 MB
    _Float16* hb    = (_Float16*)(wsb + ((size_t)72 << 20));  // 16 MB
    _Float16* qwb   = (_Float16*)(wsb + ((size_t)88 << 20));  // 384 KB
    _Float16* pwb   = (_Float16*)(wsb + ((size_t)89 << 20));  // 128 KB

    k_prep<<<4352, 256, 0, stream>>>(x, rel, qkv_w, pw, hb, qwb, pwb);
    k_qkv_gemm<<<1536, 256, 0, stream>>>(hb, qwb, qg, kg, Qg, Kg, Vtg);
    k_chunk_kv<<<2048, 64, 0, stream>>>(Kg, Vtg, kvb);
    k_scan<<<64, 256, 0, stream>>>(kvb);
    k_attn<<<2048, 256, 0, stream>>>(Qg, Kg, Vtg, kvb, attnp);
    k_proj_gemm<<<512, 256, 0, stream>>>(attnp, pwb, pb, out);
}